// Round 15
// baseline (646.395 us; speedup 1.0000x reference)
//
#include <hip/hip_runtime.h>

#define NP 784
#define DIM 384
#define NL 200000
#define WTOP_BLOCKS 512
#define WCAP 4096

#define BM 128
#define BN 128
#define BK 64
#define NSTEP 6
#define MTILES 7
#define NTILES 1563
#define MPAD (MTILES * BM)     // 896
#define NLPAD (NTILES * BN)    // 200064
#define PCOLS (NTILES * 2)     // 3126 granules of 64 j's per i
#define DELTA2 3.0f            // margin on approx val (i8 screen)
#define DELTAW 6.0f            // margin for w_dist top-3 selection
#define RESCORE_WAVES 2048

#define QS (6.5f / 127.0f)
#define QINV (127.0f / 6.5f)
#define NEG2S2 (-2.0f * QS * QS)
#define S2 (QS * QS)

#define PB_ROWS 96
#define PB_F4 (PB_ROWS * 96)       // 9216 float4 per block
#define PB_ITERS (PB_F4 / 256)     // 36
#define PB_GRID (NLPAD / PB_ROWS)  // 2084 (exact)
#define PREP_GRID (PB_GRID + MPAD / 4)  // 2308

#define SCAN_BLOCKS 96
#define GCHUNK ((PCOLS + SCAN_BLOCKS - 1) / SCAN_BLOCKS)  // 33

#define WD_WAVES (WTOP_BLOCKS * 4)                         // 2048
#define WD_CHUNK ((NL + WD_WAVES - 1) / WD_WAVES)          // 98

#define RESIZE_BLOCKS 196      // 196*256 = 50176 = 224*224

typedef __attribute__((ext_vector_type(4))) int int4v;

__device__ __forceinline__ unsigned long long packdj(float d2, int j) {
  return ((unsigned long long)__float_as_uint(d2) << 32) | (unsigned int)j;
}

__device__ __forceinline__ void ins3(unsigned long long &t0, unsigned long long &t1,
                                     unsigned long long &t2, unsigned long long p) {
  if (p < t0) { t2 = t1; t1 = t0; t0 = p; }
  else if (p < t1) { t2 = t1; t1 = p; }
  else if (p < t2) { t2 = p; }
}

// monotone f32 <-> u32 order-preserving encoding
__device__ __forceinline__ unsigned fenc(float x) {
  unsigned u = __float_as_uint(x);
  return (u & 0x80000000u) ? ~u : (u | 0x80000000u);
}
__device__ __forceinline__ float fdec(unsigned e) {
  unsigned u = (e & 0x80000000u) ? (e ^ 0x80000000u) : ~e;
  return __uint_as_float(u);
}

__device__ __forceinline__ int qclamp(float x) {
  int q = (int)rintf(x * QINV);
  return max(-127, min(127, q));
}
__device__ __forceinline__ unsigned qpack4(float4 v) {
  int q0 = qclamp(v.x), q1 = qclamp(v.y), q2 = qclamp(v.z), q3 = qclamp(v.w);
  return (unsigned)(q0 & 255) | ((unsigned)(q1 & 255) << 8) |
         ((unsigned)(q2 & 255) << 16) | ((unsigned)(q3 & 255) << 24);
}

#if __has_builtin(__builtin_amdgcn_sdot4)
__device__ __forceinline__ int dot4acc(unsigned a, unsigned b, int c) {
  return __builtin_amdgcn_sdot4((int)a, (int)b, c, false);
}
#else
__device__ __forceinline__ int dot4acc(unsigned a, unsigned b, int c) {
#pragma unroll
  for (int k = 0; k < 4; ++k)
    c += ((int)(signed char)((a >> (8 * k)) & 255)) *
         ((int)(signed char)((b >> (8 * k)) & 255));
  return c;
}
#endif
__device__ __forceinline__ int fxr(int row) { return (row ^ (row >> 2)) & 3; }

// ========== merged prep: blocks [0,PB_GRID) quantize lib; rest quantize patch ==========
__global__ __launch_bounds__(256) void k_prep(const float* __restrict__ lib,
                                              const float* __restrict__ patch,
                                              unsigned* __restrict__ Bq4,
                                              unsigned* __restrict__ Aq4,
                                              float* __restrict__ b2,
                                              float* __restrict__ a2,
                                              unsigned long long* __restrict__ pmin,
                                              unsigned int* __restrict__ cnt,
                                              unsigned int* __restrict__ gmin) {
  const int t = threadIdx.x;
  if (blockIdx.x < PB_GRID) {
    __shared__ float rs[PB_ROWS][2];
    const int w = t >> 6, lane = t & 63;
    const size_t gbase = (size_t)blockIdx.x * PB_F4;
    const int rbase = blockIdx.x * PB_ROWS;
    const float4* lib4 = (const float4*)lib;
    const size_t NF4REAL = (size_t)NL * 96;

    for (int it = 0; it < PB_ITERS; ++it) {
      int fl = it * 256 + t;
      size_t f = gbase + fl;
      float4 v = make_float4(0.f, 0.f, 0.f, 0.f);
      if (f < NF4REAL) v = lib4[f];
      float sum = fmaf(v.x, v.x, fmaf(v.y, v.y, fmaf(v.z, v.z, v.w * v.w)));
      Bq4[f] = qpack4(v);

      int wstart = it * 256 + (w << 6);
      int r0 = wstart / 96;
      int s = (r0 + 1) * 96 - wstart;          // in {32, 64, 96}
      float lo = (lane < s) ? sum : 0.f;
#pragma unroll
      for (int m = 1; m < 64; m <<= 1) lo += __shfl_xor(lo, m);
      if (lane == 0) rs[r0][(s == 96) ? 0 : 1] = lo;
      if (s == 32) {
        float hi = (lane >= 32) ? sum : 0.f;
#pragma unroll
        for (int m = 1; m < 64; m <<= 1) hi += __shfl_xor(hi, m);
        if (lane == 0) rs[r0 + 1][0] = hi;
      }
    }
    __syncthreads();
    if (t < PB_ROWS) {
      int r = rbase + t;
      b2[r] = (r < NL) ? (rs[t][0] + rs[t][1]) : INFINITY;
    }
  } else {
    int ab = blockIdx.x - PB_GRID;
    if (ab == 0) {
      for (int q = t; q < NP; q += 256) pmin[q] = ~0ull;
      for (int q = t; q < MPAD; q += 256) gmin[q] = 0xFFFFFFFFu;
      if (t < 8) cnt[t] = 0;
    }
    int i = (ab << 2) | (t >> 6);
    int lane = t & 63;
    if (i >= MPAD) return;
    unsigned* orow = Aq4 + (size_t)i * 96;
    if (i < NP) {
      const float4* r4 = (const float4*)(patch + (size_t)i * DIM);
      float s = 0.f;
      float4 v = r4[lane];
      s = fmaf(v.x, v.x, fmaf(v.y, v.y, fmaf(v.z, v.z, fmaf(v.w, v.w, s))));
      orow[lane] = qpack4(v);
      if (lane < 32) {
        float4 v1 = r4[64 + lane];
        s = fmaf(v1.x, v1.x, fmaf(v1.y, v1.y, fmaf(v1.z, v1.z, fmaf(v1.w, v1.w, s))));
        orow[64 + lane] = qpack4(v1);
      }
#pragma unroll
      for (int m = 1; m < 64; m <<= 1) s += __shfl_xor(s, m);
      if (lane == 0) a2[i] = s;
    } else {
      orow[lane] = 0u;
      if (lane < 32) orow[64 + lane] = 0u;
    }
  }
}

// ====== main: 128x128 i8 MFMA GEMM, BK=64, dbuf 2-phase prefetch [R12-verified] ======
// Epilogue now also atomicMin's the per-i global min (replaces k_colmin).
__global__ __launch_bounds__(256, 5) void k_gemm(const unsigned char* __restrict__ Aq,
                                                 const unsigned char* __restrict__ Bq,
                                                 const float* __restrict__ b2,
                                                 float* __restrict__ partial,
                                                 unsigned int* __restrict__ gmin) {
  __shared__ char sA[16384], sB[16384];   // 2 x 8KB each, 32KB total

  const int TOT = MTILES * NTILES;        // 10941
  const int q8 = TOT >> 3, r8 = TOT & 7;  // 1367, 5
  int xcd = blockIdx.x & 7, seq = blockIdx.x >> 3;
  int wg = (xcd < r8 ? xcd * (q8 + 1) : r8 * (q8 + 1) + (xcd - r8) * q8) + seq;
  int ntile = wg / MTILES;
  int mtile = wg - ntile * MTILES;
  const int i0 = mtile * BM;
  const int j0 = ntile * BN;

  const int t = threadIdx.x;
  const int w = t >> 6, lane = t & 63;
  const int wr = w >> 1, wc = w & 1;        // wave -> 64x64 sub-tile
  const int lrow = lane & 15, lk = lane >> 4;

  const char* srcs[4];
  int dslot[4];
  {
    int s0 = t, s1 = 256 + t;
    int r0 = s0 >> 2, c0 = (s0 & 3) ^ fxr(r0);
    int r1 = s1 >> 2, c1 = (s1 & 3) ^ fxr(r1);
    srcs[0] = (const char*)Aq + (size_t)(i0 + r0) * DIM + (c0 << 4);
    srcs[1] = (const char*)Aq + (size_t)(i0 + r1) * DIM + (c1 << 4);
    srcs[2] = (const char*)Bq + (size_t)(j0 + r0) * DIM + (c0 << 4);
    srcs[3] = (const char*)Bq + (size_t)(j0 + r1) * DIM + (c1 << 4);
    dslot[0] = s0 << 4; dslot[1] = s1 << 4;
    dslot[2] = s0 << 4; dslot[3] = s1 << 4;
  }

  int aoffs[4], boffs[4];
#pragma unroll
  for (int m = 0; m < 4; ++m) {
    int Ra = (wr << 6) + (m << 4) + lrow;
    aoffs[m] = (Ra << 6) + ((lk ^ fxr(Ra)) << 4);
    int Rb = (wc << 6) + (m << 4) + lrow;
    boffs[m] = (Rb << 6) + ((lk ^ fxr(Rb)) << 4);
  }

  int4v acc[4][4];
#pragma unroll
  for (int m = 0; m < 4; ++m)
#pragma unroll
    for (int n = 0; n < 4; ++n) acc[m][n] = (int4v){0, 0, 0, 0};

  __builtin_amdgcn_global_load_lds((const __attribute__((address_space(1))) void*)srcs[0],
                                   (__attribute__((address_space(3))) void*)(sA + dslot[0]), 16, 0, 0);
  __builtin_amdgcn_global_load_lds((const __attribute__((address_space(1))) void*)srcs[1],
                                   (__attribute__((address_space(3))) void*)(sA + dslot[1]), 16, 0, 0);
  __builtin_amdgcn_global_load_lds((const __attribute__((address_space(1))) void*)srcs[2],
                                   (__attribute__((address_space(3))) void*)(sB + dslot[2]), 16, 0, 0);
  __builtin_amdgcn_global_load_lds((const __attribute__((address_space(1))) void*)srcs[3],
                                   (__attribute__((address_space(3))) void*)(sB + dslot[3]), 16, 0, 0);
  __syncthreads();

#pragma unroll
  for (int step = 0; step < NSTEP; ++step) {
    const int cur = step & 1;
    const int curoff = cur << 13;
    if (step < NSTEP - 1) {
      const int nxtoff = (cur ^ 1) << 13;
      const int kb = (step + 1) << 6;
      __builtin_amdgcn_global_load_lds((const __attribute__((address_space(1))) void*)(srcs[0] + kb),
                                       (__attribute__((address_space(3))) void*)(sA + nxtoff + dslot[0]), 16, 0, 0);
      __builtin_amdgcn_global_load_lds((const __attribute__((address_space(1))) void*)(srcs[1] + kb),
                                       (__attribute__((address_space(3))) void*)(sA + nxtoff + dslot[1]), 16, 0, 0);
      __builtin_amdgcn_global_load_lds((const __attribute__((address_space(1))) void*)(srcs[2] + kb),
                                       (__attribute__((address_space(3))) void*)(sB + nxtoff + dslot[2]), 16, 0, 0);
      __builtin_amdgcn_global_load_lds((const __attribute__((address_space(1))) void*)(srcs[3] + kb),
                                       (__attribute__((address_space(3))) void*)(sB + nxtoff + dslot[3]), 16, 0, 0);
    }
    int4v fa[4], fb[4];
#pragma unroll
    for (int m = 0; m < 4; ++m) fa[m] = *(const int4v*)(sA + curoff + aoffs[m]);
#pragma unroll
    for (int n = 0; n < 4; ++n) fb[n] = *(const int4v*)(sB + curoff + boffs[n]);
#pragma unroll
    for (int m = 0; m < 4; ++m)
#pragma unroll
      for (int n = 0; n < 4; ++n)
        acc[m][n] = __builtin_amdgcn_mfma_i32_16x16x64_i8(fa[m], fb[n], acc[m][n], 0, 0, 0);
    if (step < NSTEP - 1) __syncthreads();
  }

  float b2v[4];
#pragma unroll
  for (int n = 0; n < 4; ++n) b2v[n] = b2[j0 + (wc << 6) + (n << 4) + lrow];
  const int gcol = (ntile << 1) + wc;
  float* pcol = partial + (size_t)gcol * MPAD;
#pragma unroll
  for (int m = 0; m < 4; ++m) {
    float4 v;
#pragma unroll
    for (int r = 0; r < 4; ++r) {
      float dm = INFINITY;
#pragma unroll
      for (int n = 0; n < 4; ++n)
        dm = fminf(dm, fmaf(NEG2S2, (float)acc[m][n][r], b2v[n]));
#pragma unroll
      for (int mm = 1; mm < 16; mm <<= 1)
        dm = fminf(dm, __shfl_xor(dm, mm));
      ((float*)&v)[r] = dm;
    }
    if (lrow == 0) {
      int ib = i0 + (wr << 6) + (m << 4) + (lk << 2);
      *(float4*)(pcol + ib) = v;
      // fused per-i global min (replaces k_colmin)
      atomicMin(&gmin[ib + 0], fenc(v.x));
      atomicMin(&gmin[ib + 1], fenc(v.y));
      atomicMin(&gmin[ib + 2], fenc(v.z));
      atomicMin(&gmin[ib + 3], fenc(v.w));
    }
  }
}

// ===== select candidates within margin (coalesced read) -> compacted list =====
__global__ __launch_bounds__(256) void k_select(const float* __restrict__ partial,
                                                const unsigned int* __restrict__ gmin,
                                                unsigned int* __restrict__ list,
                                                unsigned int* __restrict__ cnt) {
  int t = threadIdx.x;
  int g0 = blockIdx.x * GCHUNK;
  int g1 = min(g0 + GCHUNK, PCOLS);
  float th0 = fdec(gmin[t]) + DELTA2;
  float th1 = fdec(gmin[t + 256]) + DELTA2;
  float th2 = fdec(gmin[t + 512]) + DELTA2;
  float th3 = (t < 16) ? (fdec(gmin[t + 768]) + DELTA2) : -INFINITY;
  for (int g = g0; g < g1; ++g) {
    const float* col = partial + (size_t)g * MPAD;
    float v0 = col[t], v1 = col[t + 256], v2 = col[t + 512];
    float v3 = (t < 128) ? col[t + 768] : INFINITY;
    if (v0 <= th0) { unsigned p = atomicAdd(cnt, 1u); list[p] = ((unsigned)t << 12) | (unsigned)g; }
    if (v1 <= th1) { unsigned p = atomicAdd(cnt, 1u); list[p] = ((unsigned)(t + 256) << 12) | (unsigned)g; }
    if (v2 <= th2) { unsigned p = atomicAdd(cnt, 1u); list[p] = ((unsigned)(t + 512) << 12) | (unsigned)g; }
    if (t < 16 && v3 <= th3) { unsigned p = atomicAdd(cnt, 1u); list[p] = ((unsigned)(t + 768) << 12) | (unsigned)g; }
  }
}

// ===== exact fp32 rescore of candidate granules -> pmin (packed atomicMin) =====
__global__ __launch_bounds__(256) void k_rescore(const unsigned int* __restrict__ list,
                                                 const unsigned int* __restrict__ cnt,
                                                 const float* __restrict__ patch,
                                                 const float* __restrict__ lib,
                                                 const float* __restrict__ a2,
                                                 const float* __restrict__ b2,
                                                 unsigned long long* __restrict__ pmin) {
  int wid = (blockIdx.x << 2) | (threadIdx.x >> 6);
  int lane = threadIdx.x & 63;
  int n = (int)*cnt;
  for (int c = wid; c < n; c += RESCORE_WAVES) {
    unsigned int e = list[c];
    int i = (int)(e >> 12);
    int g = (int)(e & 4095u);
    int j = (g << 6) + lane;
    unsigned long long best = ~0ull;
    if (j < NL) {
      const float* pr = patch + (size_t)i * DIM;
      const float* lr = lib + (size_t)j * DIM;
      float d0 = 0.f, d1 = 0.f, d2s = 0.f, d3 = 0.f;
#pragma unroll 8
      for (int k = 0; k < DIM; k += 4) {
        float4 lv = *(const float4*)(lr + k);
        float4 pv = *(const float4*)(pr + k);
        d0 = fmaf(lv.x, pv.x, d0);
        d1 = fmaf(lv.y, pv.y, d1);
        d2s = fmaf(lv.z, pv.z, d2s);
        d3 = fmaf(lv.w, pv.w, d3);
      }
      float dot = (d0 + d1) + (d2s + d3);
      float d2 = fmaxf(a2[i] + b2[j] - 2.f * dot, 0.f);
      best = packdj(d2, j);
    }
#pragma unroll
    for (int mm = 1; mm < 64; mm <<= 1) {
      unsigned long long o = __shfl_xor(best, mm);
      best = (o < best) ? o : best;
    }
    if (lane == 0) atomicMin(pmin + i, best);
  }
}

// ===== fused finalize + resize: blocks 0..195 resize; block 196 computes s_star/s_idx =====
__global__ __launch_bounds__(256) void k_finres(const unsigned long long* __restrict__ pmin,
                                                float* __restrict__ scalf,
                                                int* __restrict__ scali,
                                                float* __restrict__ out) {
  int t = threadIdx.x;
  if (blockIdx.x < RESIZE_BLOCKS) {
    int o = blockIdx.x * 256 + t;
    int y = o / 224, x = o - y * 224;
    float sy = (y + 0.5f) * 0.125f - 0.5f;
    float sx = (x + 0.5f) * 0.125f - 0.5f;
    int y0 = (int)floorf(sy); float fy = sy - (float)y0;
    int x0 = (int)floorf(sx); float fx = sx - (float)x0;
    int y0c = max(y0, 0), y1c = min(y0 + 1, 27);
    int x0c = max(x0, 0), x1c = min(x0 + 1, 27);
#define MV(idx) sqrtf(__uint_as_float((unsigned int)(pmin[idx] >> 32)))
    float v00 = MV(y0c * 28 + x0c), v01 = MV(y0c * 28 + x1c);
    float v10 = MV(y1c * 28 + x0c), v11 = MV(y1c * 28 + x1c);
#undef MV
    float v0 = v00 + fx * (v01 - v00);
    float v1 = v10 + fx * (v11 - v10);
    out[1 + o] = v0 + fy * (v1 - v0);
  } else {
    __shared__ float sv[256];
    __shared__ int si[256];
    float bv = -1.f; int bi = 1 << 30;
    for (int i = t; i < NP; i += 256) {
      float v = sqrtf(__uint_as_float((unsigned int)(pmin[i] >> 32)));
      if (v > bv) { bv = v; bi = i; }
    }
    sv[t] = bv; si[t] = bi;
    __syncthreads();
    for (int s = 128; s > 0; s >>= 1) {
      if (t < s) {
        if (sv[t + s] > sv[t] || (sv[t + s] == sv[t] && si[t + s] < si[t])) {
          sv[t] = sv[t + s]; si[t] = si[t + s];
        }
      }
      __syncthreads();
    }
    if (t == 0) {
      scalf[0] = sv[0];
      scali[0] = si[0];
      scali[1] = (int)(unsigned int)(pmin[si[0]] & 0xFFFFFFFFull);
    }
  }
}

// ===== approx w_dist^2: contiguous per-wave chunks, 2-row unrolled [R14-verified] =====
__global__ __launch_bounds__(256) void k_wdist(const unsigned* __restrict__ Bq4,
                                               const float* __restrict__ b2,
                                               const int* __restrict__ scali,
                                               float* __restrict__ wd2,
                                               unsigned long long* __restrict__ top3w) {
  __shared__ unsigned long long sm[12];
  int wave = threadIdx.x >> 6, lane = threadIdx.x & 63;
  int jstar = scali[1];
  const unsigned* msrow = Bq4 + (size_t)jstar * 96;
  unsigned m0 = msrow[lane];
  unsigned m1 = (lane < 32) ? msrow[64 + lane] : 0u;
  float bstar = b2[jstar];
  unsigned long long t0 = ~0ull, t1 = ~0ull, t2 = ~0ull;
  int wid = (blockIdx.x << 2) | wave;
  int r0 = wid * WD_CHUNK;
  int rend = min(r0 + WD_CHUNK, NL);
  for (int j = r0; j + 1 < rend; j += 2) {
    const unsigned* rowa = Bq4 + (size_t)j * 96;
    const unsigned* rowb = rowa + 96;
    unsigned a0 = rowa[lane], b0 = rowb[lane];
    unsigned a1 = 0u, b1 = 0u;
    if (lane < 32) { a1 = rowa[64 + lane]; b1 = rowb[64 + lane]; }
    int ia = dot4acc(m0, a0, 0);
    int ib = dot4acc(m0, b0, 0);
    if (lane < 32) { ia = dot4acc(m1, a1, ia); ib = dot4acc(m1, b1, ib); }
#pragma unroll
    for (int mm = 1; mm < 64; mm <<= 1) {
      ia += __shfl_xor(ia, mm);
      ib += __shfl_xor(ib, mm);
    }
    float d2a = fmaxf(bstar + b2[j] - 2.f * S2 * (float)ia, 0.f);
    float d2b = fmaxf(bstar + b2[j + 1] - 2.f * S2 * (float)ib, 0.f);
    if (lane == 0) { wd2[j] = d2a; wd2[j + 1] = d2b; }
    ins3(t0, t1, t2, packdj(d2a, j));
    ins3(t0, t1, t2, packdj(d2b, j + 1));
  }
  if ((rend - r0) & 1) {
    int j = rend - 1;
    const unsigned* row = Bq4 + (size_t)j * 96;
    int id = dot4acc(m0, row[lane], 0);
    if (lane < 32) id = dot4acc(m1, row[64 + lane], id);
#pragma unroll
    for (int mm = 1; mm < 64; mm <<= 1) id += __shfl_xor(id, mm);
    float d2 = fmaxf(bstar + b2[j] - 2.f * S2 * (float)id, 0.f);
    if (lane == 0) wd2[j] = d2;
    ins3(t0, t1, t2, packdj(d2, j));
  }
  if (lane == 0) { sm[wave * 3] = t0; sm[wave * 3 + 1] = t1; sm[wave * 3 + 2] = t2; }
  __syncthreads();
  if (threadIdx.x == 0) {
    unsigned long long a0 = ~0ull, a1 = ~0ull, a2v = ~0ull;
    for (int e = 0; e < 12; ++e) ins3(a0, a1, a2v, sm[e]);
    top3w[blockIdx.x * 3 + 0] = a0;
    top3w[blockIdx.x * 3 + 1] = a1;
    top3w[blockIdx.x * 3 + 2] = a2v;
  }
}

// ===== merge approx top-3 -> threshold [verified R5/R12] =====
__global__ __launch_bounds__(256) void k_wsel1(const unsigned long long* __restrict__ top3w,
                                               float* __restrict__ scalf) {
  __shared__ unsigned long long sm[768];
  int t = threadIdx.x;
  unsigned long long t0 = ~0ull, t1 = ~0ull, t2 = ~0ull;
  for (int e = t; e < WTOP_BLOCKS * 3; e += 256) ins3(t0, t1, t2, top3w[e]);
  sm[t] = t0; sm[256 + t] = t1; sm[512 + t] = t2;
  __syncthreads();
  if (t == 0) {
    unsigned long long a0 = ~0ull, a1 = ~0ull, a2v = ~0ull;
    for (int e = 0; e < 768; ++e) ins3(a0, a1, a2v, sm[e]);
    scalf[1] = __uint_as_float((unsigned int)(a2v >> 32)) + DELTAW;
  }
}

// ===== collect all j with wd2 <= thr [verified R5] =====
__global__ __launch_bounds__(256) void k_wsel2(const float* __restrict__ wd2,
                                               const float* __restrict__ scalf,
                                               unsigned int* __restrict__ wlist,
                                               unsigned int* __restrict__ wcnt) {
  float thr = scalf[1];
  for (int j = blockIdx.x * 256 + threadIdx.x; j < NL; j += 256 * 256) {
    if (wd2[j] <= thr) {
      unsigned int pos = atomicAdd(wcnt, 1u);
      if (pos < WCAP) wlist[pos] = (unsigned int)j;
    }
  }
}

// ===== exact rescore of w candidates -> top-3 -> final s [verified R5] =====
__global__ __launch_bounds__(256) void k_finals2(const float* __restrict__ patch,
                                                 const float* __restrict__ lib,
                                                 const float* __restrict__ b2,
                                                 const unsigned int* __restrict__ wlist,
                                                 const unsigned int* __restrict__ wcnt,
                                                 const float* __restrict__ scalf,
                                                 const int* __restrict__ scali,
                                                 float* __restrict__ out) {
  __shared__ unsigned long long pk[WCAP];
  __shared__ int snn[2];
  __shared__ float sd[2];
  int t = threadIdx.x, wv = t >> 6, lane = t & 63;
  int n = min((int)*wcnt, WCAP);
  int jstar = scali[1];
  const float* mstar = lib + (size_t)jstar * DIM;
  float bstar = b2[jstar];
  for (int c = wv; c < n; c += 4) {
    int j = (int)wlist[c];
    const float* lr = lib + (size_t)j * DIM;
    float s = 0.f;
#pragma unroll
    for (int q = 0; q < 6; ++q)
      s = fmaf(mstar[lane + (q << 6)], lr[lane + (q << 6)], s);
#pragma unroll
    for (int mm = 1; mm < 64; mm <<= 1) s += __shfl_xor(s, mm);
    if (lane == 0) pk[c] = packdj(fmaxf(bstar + b2[j] - 2.f * s, 0.f), j);
  }
  __syncthreads();
  if (t == 0) {
    unsigned long long a0 = ~0ull, a1 = ~0ull, a2v = ~0ull;
    for (int e = 0; e < n; ++e) ins3(a0, a1, a2v, pk[e]);
    snn[0] = (int)(unsigned int)(a1 & 0xFFFFFFFFull);
    snn[1] = (int)(unsigned int)(a2v & 0xFFFFFFFFull);
  }
  __syncthreads();
  if (t < 128) {
    const float* mt = patch + (size_t)scali[0] * DIM;
    const float* bp = lib + (size_t)snn[wv] * DIM;
    float s = 0.f;
#pragma unroll
    for (int q = 0; q < 6; ++q) {
      float d = mt[lane + (q << 6)] - bp[lane + (q << 6)];
      s = fmaf(d, d, s);
    }
#pragma unroll
    for (int mm = 1; mm < 64; mm <<= 1) s += __shfl_xor(s, mm);
    if (lane == 0) sd[wv] = sqrtf(fmaxf(s, 0.f));
  }
  __syncthreads();
  if (t == 0) {
    const float Ds = 19.595917942265423f;  // sqrt(384)
    float sstar = scalf[0];
    float w = 1.f - expf(sstar / Ds) / (expf(sd[0] / Ds) + expf(sd[1] / Ds));
    out[0] = w * sstar;
  }
}

// ======= fallback fp32 path kernels (used only if ws_size is too small) =======
__global__ __launch_bounds__(256) void k_norms(const float* __restrict__ patch,
                                               const float* __restrict__ lib,
                                               float* __restrict__ a2,
                                               float* __restrict__ b2) {
  int wave = (blockIdx.x << 2) | (threadIdx.x >> 6);
  int lane = threadIdx.x & 63;
  const int NR = NL + NP;
  if (wave >= NR) return;
  const float* src = (wave < NL) ? (lib + (size_t)wave * DIM)
                                 : (patch + (size_t)(wave - NL) * DIM);
  float s = 0.f;
#pragma unroll
  for (int m = 0; m < 6; ++m) { float v = src[lane + (m << 6)]; s += v * v; }
#pragma unroll
  for (int m = 1; m < 64; m <<= 1) s += __shfl_xor(s, m);
  if (lane == 0) { if (wave < NL) b2[wave] = s; else a2[wave - NL] = s; }
}

__global__ __launch_bounds__(256) void k_distmin(const float* __restrict__ patch,
                                                 const float* __restrict__ lib,
                                                 const float* __restrict__ a2,
                                                 const float* __restrict__ b2,
                                                 unsigned long long* __restrict__ pmin) {
  __shared__ float As[16][68];
  __shared__ float Bs[16][68];
  const int t = threadIdx.x;
  const int lr = t >> 2;
  const int lc = (t & 3) << 2;
  const int ti = t >> 4;
  const int tj = t & 15;
  const int i0 = blockIdx.y << 6;
  const int j0 = blockIdx.x << 6;
  const bool a_ok = (i0 + lr) < NP;
  const float* ap = patch + (size_t)(i0 + lr) * DIM + lc;
  const float* bp = lib + (size_t)(j0 + lr) * DIM + lc;

  float acc[4][4] = {};
  for (int k0 = 0; k0 < DIM; k0 += 16) {
    float4 avv = make_float4(0.f, 0.f, 0.f, 0.f);
    if (a_ok) avv = *(const float4*)(ap + k0);
    float4 bvv = *(const float4*)(bp + k0);
    __syncthreads();
    As[lc + 0][lr] = avv.x; As[lc + 1][lr] = avv.y;
    As[lc + 2][lr] = avv.z; As[lc + 3][lr] = avv.w;
    Bs[lc + 0][lr] = bvv.x; Bs[lc + 1][lr] = bvv.y;
    Bs[lc + 2][lr] = bvv.z; Bs[lc + 3][lr] = bvv.w;
    __syncthreads();
#pragma unroll
    for (int kk = 0; kk < 16; ++kk) {
      float4 a = *(const float4*)&As[kk][ti << 2];
      float4 b = *(const float4*)&Bs[kk][tj << 2];
      acc[0][0] += a.x * b.x; acc[0][1] += a.x * b.y; acc[0][2] += a.x * b.z; acc[0][3] += a.x * b.w;
      acc[1][0] += a.y * b.x; acc[1][1] += a.y * b.y; acc[1][2] += a.y * b.z; acc[1][3] += a.y * b.w;
      acc[2][0] += a.z * b.x; acc[2][1] += a.z * b.y; acc[2][2] += a.z * b.z; acc[2][3] += a.z * b.w;
      acc[3][0] += a.w * b.x; acc[3][1] += a.w * b.y; acc[3][2] += a.w * b.z; acc[3][3] += a.w * b.w;
    }
  }
#pragma unroll
  for (int r = 0; r < 4; ++r) {
    int i = i0 + (ti << 2) + r;
    unsigned long long best = ~0ull;
    if (i < NP) {
      float ai = a2[i];
#pragma unroll
      for (int c = 0; c < 4; ++c) {
        int j = j0 + (tj << 2) + c;
        float d2 = fmaxf(ai + b2[j] - 2.f * acc[r][c], 0.f);
        unsigned long long p = packdj(d2, j);
        best = (p < best) ? p : best;
      }
    }
#pragma unroll
    for (int m = 1; m < 16; m <<= 1) {
      unsigned long long o = __shfl_xor(best, m);
      best = (o < best) ? o : best;
    }
    if (tj == 0 && i < NP) atomicMin(pmin + i, best);
  }
}

__global__ __launch_bounds__(256) void k_wtop(const float* __restrict__ lib,
                                              const int* __restrict__ scali,
                                              unsigned long long* __restrict__ top3) {
  __shared__ unsigned long long sm[12];
  int wave = threadIdx.x >> 6, lane = threadIdx.x & 63;
  int jstar = scali[1];
  const float* ms = lib + (size_t)jstar * DIM;
  float m[6];
#pragma unroll
  for (int q = 0; q < 6; ++q) m[q] = ms[lane + (q << 6)];
  unsigned long long t0 = ~0ull, t1 = ~0ull, t2 = ~0ull;
  int gw = (blockIdx.x << 2) | wave;
  for (int j = gw; j < NL; j += WTOP_BLOCKS * 4) {
    const float* bp = lib + (size_t)j * DIM;
    float s = 0.f;
#pragma unroll
    for (int q = 0; q < 6; ++q) { float d = bp[lane + (q << 6)] - m[q]; s += d * d; }
#pragma unroll
    for (int mm = 1; mm < 64; mm <<= 1) s += __shfl_xor(s, mm);
    ins3(t0, t1, t2, packdj(fmaxf(s, 0.f), j));
  }
  if (lane == 0) { sm[wave * 3] = t0; sm[wave * 3 + 1] = t1; sm[wave * 3 + 2] = t2; }
  __syncthreads();
  if (threadIdx.x == 0) {
    unsigned long long a0 = ~0ull, a1 = ~0ull, a2v = ~0ull;
    for (int e = 0; e < 12; ++e) ins3(a0, a1, a2v, sm[e]);
    top3[blockIdx.x * 3 + 0] = a0;
    top3[blockIdx.x * 3 + 1] = a1;
    top3[blockIdx.x * 3 + 2] = a2v;
  }
}

__global__ __launch_bounds__(256) void k_finals(const float* __restrict__ patch,
                                                const float* __restrict__ lib,
                                                const unsigned long long* __restrict__ top3,
                                                const float* __restrict__ scalf,
                                                const int* __restrict__ scali,
                                                float* __restrict__ out) {
  __shared__ unsigned long long sm[768];
  __shared__ int snn[2];
  __shared__ float sd[2];
  int t = threadIdx.x;
  unsigned long long t0 = ~0ull, t1 = ~0ull, t2 = ~0ull;
  for (int e = t; e < WTOP_BLOCKS * 3; e += 256) ins3(t0, t1, t2, top3[e]);
  sm[t] = t0; sm[256 + t] = t1; sm[512 + t] = t2;
  __syncthreads();
  if (t == 0) {
    unsigned long long a0 = ~0ull, a1 = ~0ull, a2v = ~0ull;
    for (int e = 0; e < 768; ++e) ins3(a0, a1, a2v, sm[e]);
    snn[0] = (int)(unsigned int)(a1 & 0xFFFFFFFFull);
    snn[1] = (int)(unsigned int)(a2v & 0xFFFFFFFFull);
  }
  __syncthreads();
  if (t < 128) {
    int wv = t >> 6, lane = t & 63;
    const float* mt = patch + (size_t)scali[0] * DIM;
    const float* bp = lib + (size_t)snn[wv] * DIM;
    float s = 0.f;
#pragma unroll
    for (int q = 0; q < 6; ++q) {
      float d = mt[lane + (q << 6)] - bp[lane + (q << 6)];
      s += d * d;
    }
#pragma unroll
    for (int mm = 1; mm < 64; mm <<= 1) s += __shfl_xor(s, mm);
    if (lane == 0) sd[wv] = sqrtf(fmaxf(s, 0.f));
  }
  __syncthreads();
  if (t == 0) {
    const float Ds = 19.595917942265423f;
    float sstar = scalf[0];
    float w = 1.f - expf(sstar / Ds) / (expf(sd[0] / Ds) + expf(sd[1] / Ds));
    out[0] = w * sstar;
  }
}

extern "C" void kernel_launch(void* const* d_in, const int* in_sizes, int n_in,
                              void* d_out, int out_size, void* d_ws, size_t ws_size,
                              hipStream_t stream) {
  const float* patch = (const float*)d_in[0];
  const float* lib = (const float*)d_in[1];
  float* out = (float*)d_out;
  char* ws = (char*)d_ws;

  const size_t SZ_BPLANE = (size_t)NLPAD * DIM;              // 76,824,576 (int8)
  const size_t SZ_APLANE = (size_t)MPAD * DIM;               // 344,064 (int8)
  const size_t SZ_PART = (size_t)PCOLS * MPAD * 4;           // 11,203,584
  const size_t SZ_LIST = (size_t)NP * PCOLS * 4;             // 9,803,136
  const size_t SZ_WD2 = (size_t)NLPAD * 4;                   // 800,256
  const size_t NEED = SZ_BPLANE + SZ_APLANE + SZ_PART + SZ_LIST + SZ_WD2 + 4 * 1024 * 1024;

  if (ws_size >= NEED) {
    size_t off = 0;
    unsigned char* Bq = (unsigned char*)(ws + off); off += SZ_BPLANE;
    unsigned char* Aq = (unsigned char*)(ws + off); off += SZ_APLANE;
    float* partial = (float*)(ws + off); off += SZ_PART;
    unsigned int* list = (unsigned int*)(ws + off); off += SZ_LIST;
    float* wd2 = (float*)(ws + off); off += SZ_WD2;
    float* b2 = (float*)(ws + off); off += (size_t)NLPAD * 4;
    float* a2 = (float*)(ws + off); off += (size_t)MPAD * 4;
    unsigned long long* pmin = (unsigned long long*)(ws + off); off += NP * 8;
    unsigned long long* top3w = (unsigned long long*)(ws + off); off += WTOP_BLOCKS * 3 * 8;
    unsigned int* wlist = (unsigned int*)(ws + off); off += WCAP * 4;
    unsigned int* gmin = (unsigned int*)(ws + off); off += MPAD * 4;
    float* scalf = (float*)(ws + off); off += 16;
    int* scali = (int*)(ws + off); off += 16;
    unsigned int* cnt = (unsigned int*)(ws + off); off += 32;  // [0]=cnt [1]=wcnt

    k_prep<<<PREP_GRID, 256, 0, stream>>>(lib, patch, (unsigned*)Bq, (unsigned*)Aq,
                                          b2, a2, pmin, cnt, gmin);
    k_gemm<<<MTILES * NTILES, 256, 0, stream>>>(Aq, Bq, b2, partial, gmin);
    k_select<<<SCAN_BLOCKS, 256, 0, stream>>>(partial, gmin, list, cnt);
    k_rescore<<<RESCORE_WAVES / 4, 256, 0, stream>>>(list, cnt, patch, lib, a2, b2, pmin);
    k_finres<<<RESIZE_BLOCKS + 1, 256, 0, stream>>>(pmin, scalf, scali, out);
    k_wdist<<<WTOP_BLOCKS, 256, 0, stream>>>((unsigned*)Bq, b2, scali, wd2, top3w);
    k_wsel1<<<1, 256, 0, stream>>>(top3w, scalf);
    k_wsel2<<<256, 256, 0, stream>>>(wd2, scalf, wlist, cnt + 1);
    k_finals2<<<1, 256, 0, stream>>>(patch, lib, b2, wlist, cnt + 1, scalf, scali, out);
  } else {
    // fallback: fp32 VALU path (verified R1)
    float* b2 = (float*)ws;
    float* a2 = (float*)(ws + 800000);
    unsigned long long* pmin = (unsigned long long*)(ws + 803200);
    unsigned long long* top3 = (unsigned long long*)(ws + 809472);
    float* scalf = (float*)(ws + 824896);
    int* scali = (int*)(ws + 824912);

    hipMemsetAsync(pmin, 0xFF, NP * sizeof(unsigned long long), stream);
    k_norms<<<(NL + NP + 3) / 4, 256, 0, stream>>>(patch, lib, a2, b2);
    dim3 grid(NL / 64, (NP + 63) / 64);
    k_distmin<<<grid, 256, 0, stream>>>(patch, lib, a2, b2, pmin);
    // fallback finalize via k_finres block-196 path + resize blocks
    k_finres<<<RESIZE_BLOCKS + 1, 256, 0, stream>>>(pmin, scalf, scali, out);
    k_wtop<<<WTOP_BLOCKS, 256, 0, stream>>>(lib, scali, top3);
    k_finals<<<1, 256, 0, stream>>>(patch, lib, top3, scalf, scali, out);
  }
}

// Round 16
// 631.279 us; speedup vs baseline: 1.0239x; 1.0239x over previous
//
#include <hip/hip_runtime.h>

#define NP 784
#define DIM 384
#define NL 200000
#define WTOP_BLOCKS 512
#define WCAP 4096

#define BM 128
#define BN 128
#define BK 64
#define NSTEP 6
#define MTILES 7
#define NTILES 1563
#define MPAD (MTILES * BM)     // 896
#define NLPAD (NTILES * BN)    // 200064
#define PCOLS (NTILES * 2)     // 3126 granules of 64 j's per i
#define DELTA2 3.0f            // margin on approx val (i8 screen)
#define DELTAW 6.0f            // margin for w_dist top-3 selection
#define RESCORE_WAVES 2048

#define QS (6.5f / 127.0f)
#define QINV (127.0f / 6.5f)
#define NEG2S2 (-2.0f * QS * QS)
#define S2 (QS * QS)

#define PB_ROWS 96
#define PB_F4 (PB_ROWS * 96)       // 9216 float4 per block
#define PB_ITERS (PB_F4 / 256)     // 36
#define PB_GRID (NLPAD / PB_ROWS)  // 2084 (exact)
#define PREP_GRID (PB_GRID + MPAD / 4)  // 2308

#define SCAN_BLOCKS 96
#define GCHUNK ((PCOLS + SCAN_BLOCKS - 1) / SCAN_BLOCKS)  // 33

#define WD_WAVES (WTOP_BLOCKS * 4)                         // 2048
#define WD_CHUNK ((NL + WD_WAVES - 1) / WD_WAVES)          // 98

#define RESIZE_BLOCKS 196      // 196*256 = 50176 = 224*224

typedef __attribute__((ext_vector_type(4))) int int4v;

__device__ __forceinline__ unsigned long long packdj(float d2, int j) {
  return ((unsigned long long)__float_as_uint(d2) << 32) | (unsigned int)j;
}

__device__ __forceinline__ void ins3(unsigned long long &t0, unsigned long long &t1,
                                     unsigned long long &t2, unsigned long long p) {
  if (p < t0) { t2 = t1; t1 = t0; t0 = p; }
  else if (p < t1) { t2 = t1; t1 = p; }
  else if (p < t2) { t2 = p; }
}

// monotone f32 <-> u32 order-preserving encoding
__device__ __forceinline__ unsigned fenc(float x) {
  unsigned u = __float_as_uint(x);
  return (u & 0x80000000u) ? ~u : (u | 0x80000000u);
}
__device__ __forceinline__ float fdec(unsigned e) {
  unsigned u = (e & 0x80000000u) ? (e ^ 0x80000000u) : ~e;
  return __uint_as_float(u);
}

__device__ __forceinline__ int qclamp(float x) {
  int q = (int)rintf(x * QINV);
  return max(-127, min(127, q));
}
__device__ __forceinline__ unsigned qpack4(float4 v) {
  int q0 = qclamp(v.x), q1 = qclamp(v.y), q2 = qclamp(v.z), q3 = qclamp(v.w);
  return (unsigned)(q0 & 255) | ((unsigned)(q1 & 255) << 8) |
         ((unsigned)(q2 & 255) << 16) | ((unsigned)(q3 & 255) << 24);
}

#if __has_builtin(__builtin_amdgcn_sdot4)
__device__ __forceinline__ int dot4acc(unsigned a, unsigned b, int c) {
  return __builtin_amdgcn_sdot4((int)a, (int)b, c, false);
}
#else
__device__ __forceinline__ int dot4acc(unsigned a, unsigned b, int c) {
#pragma unroll
  for (int k = 0; k < 4; ++k)
    c += ((int)(signed char)((a >> (8 * k)) & 255)) *
         ((int)(signed char)((b >> (8 * k)) & 255));
  return c;
}
#endif
__device__ __forceinline__ int fxr(int row) { return (row ^ (row >> 2)) & 3; }

// ========== merged prep: blocks [0,PB_GRID) quantize lib; rest quantize patch ==========
__global__ __launch_bounds__(256) void k_prep(const float* __restrict__ lib,
                                              const float* __restrict__ patch,
                                              unsigned* __restrict__ Bq4,
                                              unsigned* __restrict__ Aq4,
                                              float* __restrict__ b2,
                                              float* __restrict__ a2,
                                              unsigned long long* __restrict__ pmin,
                                              unsigned int* __restrict__ cnt,
                                              unsigned int* __restrict__ gmin) {
  const int t = threadIdx.x;
  if (blockIdx.x < PB_GRID) {
    __shared__ float rs[PB_ROWS][2];
    const int w = t >> 6, lane = t & 63;
    const size_t gbase = (size_t)blockIdx.x * PB_F4;
    const int rbase = blockIdx.x * PB_ROWS;
    const float4* lib4 = (const float4*)lib;
    const size_t NF4REAL = (size_t)NL * 96;

    for (int it = 0; it < PB_ITERS; ++it) {
      int fl = it * 256 + t;
      size_t f = gbase + fl;
      float4 v = make_float4(0.f, 0.f, 0.f, 0.f);
      if (f < NF4REAL) v = lib4[f];
      float sum = fmaf(v.x, v.x, fmaf(v.y, v.y, fmaf(v.z, v.z, v.w * v.w)));
      Bq4[f] = qpack4(v);

      int wstart = it * 256 + (w << 6);
      int r0 = wstart / 96;
      int s = (r0 + 1) * 96 - wstart;          // in {32, 64, 96}
      float lo = (lane < s) ? sum : 0.f;
#pragma unroll
      for (int m = 1; m < 64; m <<= 1) lo += __shfl_xor(lo, m);
      if (lane == 0) rs[r0][(s == 96) ? 0 : 1] = lo;
      if (s == 32) {
        float hi = (lane >= 32) ? sum : 0.f;
#pragma unroll
        for (int m = 1; m < 64; m <<= 1) hi += __shfl_xor(hi, m);
        if (lane == 0) rs[r0 + 1][0] = hi;
      }
    }
    __syncthreads();
    if (t < PB_ROWS) {
      int r = rbase + t;
      b2[r] = (r < NL) ? (rs[t][0] + rs[t][1]) : INFINITY;
    }
  } else {
    int ab = blockIdx.x - PB_GRID;
    if (ab == 0) {
      for (int q = t; q < NP; q += 256) pmin[q] = ~0ull;
      for (int q = t; q < MPAD; q += 256) gmin[q] = 0xFFFFFFFFu;
      if (t < 8) cnt[t] = 0;
    }
    int i = (ab << 2) | (t >> 6);
    int lane = t & 63;
    if (i >= MPAD) return;
    unsigned* orow = Aq4 + (size_t)i * 96;
    if (i < NP) {
      const float4* r4 = (const float4*)(patch + (size_t)i * DIM);
      float s = 0.f;
      float4 v = r4[lane];
      s = fmaf(v.x, v.x, fmaf(v.y, v.y, fmaf(v.z, v.z, fmaf(v.w, v.w, s))));
      orow[lane] = qpack4(v);
      if (lane < 32) {
        float4 v1 = r4[64 + lane];
        s = fmaf(v1.x, v1.x, fmaf(v1.y, v1.y, fmaf(v1.z, v1.z, fmaf(v1.w, v1.w, s))));
        orow[64 + lane] = qpack4(v1);
      }
#pragma unroll
      for (int m = 1; m < 64; m <<= 1) s += __shfl_xor(s, m);
      if (lane == 0) a2[i] = s;
    } else {
      orow[lane] = 0u;
      if (lane < 32) orow[64 + lane] = 0u;
    }
  }
}

// ====== main: 128x128 i8 MFMA GEMM, BK=64, dbuf 2-phase prefetch [R12/R14-verified] ======
// launch_bounds (256,4): R15's (256,5) forced VGPR 48 + scratch spill (WRITE 338MB) — reverted.
__global__ __launch_bounds__(256, 4) void k_gemm(const unsigned char* __restrict__ Aq,
                                                 const unsigned char* __restrict__ Bq,
                                                 const float* __restrict__ b2,
                                                 float* __restrict__ partial,
                                                 unsigned int* __restrict__ gmin) {
  __shared__ char sA[16384], sB[16384];   // 2 x 8KB each, 32KB total

  const int TOT = MTILES * NTILES;        // 10941
  const int q8 = TOT >> 3, r8 = TOT & 7;  // 1367, 5
  int xcd = blockIdx.x & 7, seq = blockIdx.x >> 3;
  int wg = (xcd < r8 ? xcd * (q8 + 1) : r8 * (q8 + 1) + (xcd - r8) * q8) + seq;
  int ntile = wg / MTILES;
  int mtile = wg - ntile * MTILES;
  const int i0 = mtile * BM;
  const int j0 = ntile * BN;

  const int t = threadIdx.x;
  const int w = t >> 6, lane = t & 63;
  const int wr = w >> 1, wc = w & 1;        // wave -> 64x64 sub-tile
  const int lrow = lane & 15, lk = lane >> 4;

  const char* srcs[4];
  int dslot[4];
  {
    int s0 = t, s1 = 256 + t;
    int r0 = s0 >> 2, c0 = (s0 & 3) ^ fxr(r0);
    int r1 = s1 >> 2, c1 = (s1 & 3) ^ fxr(r1);
    srcs[0] = (const char*)Aq + (size_t)(i0 + r0) * DIM + (c0 << 4);
    srcs[1] = (const char*)Aq + (size_t)(i0 + r1) * DIM + (c1 << 4);
    srcs[2] = (const char*)Bq + (size_t)(j0 + r0) * DIM + (c0 << 4);
    srcs[3] = (const char*)Bq + (size_t)(j0 + r1) * DIM + (c1 << 4);
    dslot[0] = s0 << 4; dslot[1] = s1 << 4;
    dslot[2] = s0 << 4; dslot[3] = s1 << 4;
  }

  int aoffs[4], boffs[4];
#pragma unroll
  for (int m = 0; m < 4; ++m) {
    int Ra = (wr << 6) + (m << 4) + lrow;
    aoffs[m] = (Ra << 6) + ((lk ^ fxr(Ra)) << 4);
    int Rb = (wc << 6) + (m << 4) + lrow;
    boffs[m] = (Rb << 6) + ((lk ^ fxr(Rb)) << 4);
  }

  int4v acc[4][4];
#pragma unroll
  for (int m = 0; m < 4; ++m)
#pragma unroll
    for (int n = 0; n < 4; ++n) acc[m][n] = (int4v){0, 0, 0, 0};

  __builtin_amdgcn_global_load_lds((const __attribute__((address_space(1))) void*)srcs[0],
                                   (__attribute__((address_space(3))) void*)(sA + dslot[0]), 16, 0, 0);
  __builtin_amdgcn_global_load_lds((const __attribute__((address_space(1))) void*)srcs[1],
                                   (__attribute__((address_space(3))) void*)(sA + dslot[1]), 16, 0, 0);
  __builtin_amdgcn_global_load_lds((const __attribute__((address_space(1))) void*)srcs[2],
                                   (__attribute__((address_space(3))) void*)(sB + dslot[2]), 16, 0, 0);
  __builtin_amdgcn_global_load_lds((const __attribute__((address_space(1))) void*)srcs[3],
                                   (__attribute__((address_space(3))) void*)(sB + dslot[3]), 16, 0, 0);
  __syncthreads();

#pragma unroll
  for (int step = 0; step < NSTEP; ++step) {
    const int cur = step & 1;
    const int curoff = cur << 13;
    if (step < NSTEP - 1) {
      const int nxtoff = (cur ^ 1) << 13;
      const int kb = (step + 1) << 6;
      __builtin_amdgcn_global_load_lds((const __attribute__((address_space(1))) void*)(srcs[0] + kb),
                                       (__attribute__((address_space(3))) void*)(sA + nxtoff + dslot[0]), 16, 0, 0);
      __builtin_amdgcn_global_load_lds((const __attribute__((address_space(1))) void*)(srcs[1] + kb),
                                       (__attribute__((address_space(3))) void*)(sA + nxtoff + dslot[1]), 16, 0, 0);
      __builtin_amdgcn_global_load_lds((const __attribute__((address_space(1))) void*)(srcs[2] + kb),
                                       (__attribute__((address_space(3))) void*)(sB + nxtoff + dslot[2]), 16, 0, 0);
      __builtin_amdgcn_global_load_lds((const __attribute__((address_space(1))) void*)(srcs[3] + kb),
                                       (__attribute__((address_space(3))) void*)(sB + nxtoff + dslot[3]), 16, 0, 0);
    }
    int4v fa[4], fb[4];
#pragma unroll
    for (int m = 0; m < 4; ++m) fa[m] = *(const int4v*)(sA + curoff + aoffs[m]);
#pragma unroll
    for (int n = 0; n < 4; ++n) fb[n] = *(const int4v*)(sB + curoff + boffs[n]);
#pragma unroll
    for (int m = 0; m < 4; ++m)
#pragma unroll
      for (int n = 0; n < 4; ++n)
        acc[m][n] = __builtin_amdgcn_mfma_i32_16x16x64_i8(fa[m], fb[n], acc[m][n], 0, 0, 0);
    if (step < NSTEP - 1) __syncthreads();
  }

  float b2v[4];
#pragma unroll
  for (int n = 0; n < 4; ++n) b2v[n] = b2[j0 + (wc << 6) + (n << 4) + lrow];
  const int gcol = (ntile << 1) + wc;
  float* pcol = partial + (size_t)gcol * MPAD;
#pragma unroll
  for (int m = 0; m < 4; ++m) {
    float4 v;
#pragma unroll
    for (int r = 0; r < 4; ++r) {
      float dm = INFINITY;
#pragma unroll
      for (int n = 0; n < 4; ++n)
        dm = fminf(dm, fmaf(NEG2S2, (float)acc[m][n][r], b2v[n]));
#pragma unroll
      for (int mm = 1; mm < 16; mm <<= 1)
        dm = fminf(dm, __shfl_xor(dm, mm));
      ((float*)&v)[r] = dm;
    }
    if (lrow == 0) {
      int ib = i0 + (wr << 6) + (m << 4) + (lk << 2);
      *(float4*)(pcol + ib) = v;
      atomicMin(&gmin[ib + 0], fenc(v.x));
      atomicMin(&gmin[ib + 1], fenc(v.y));
      atomicMin(&gmin[ib + 2], fenc(v.z));
      atomicMin(&gmin[ib + 3], fenc(v.w));
    }
  }
}

// ===== select candidates within margin (coalesced read) -> compacted list =====
__global__ __launch_bounds__(256) void k_select(const float* __restrict__ partial,
                                                const unsigned int* __restrict__ gmin,
                                                unsigned int* __restrict__ list,
                                                unsigned int* __restrict__ cnt) {
  int t = threadIdx.x;
  int g0 = blockIdx.x * GCHUNK;
  int g1 = min(g0 + GCHUNK, PCOLS);
  float th0 = fdec(gmin[t]) + DELTA2;
  float th1 = fdec(gmin[t + 256]) + DELTA2;
  float th2 = fdec(gmin[t + 512]) + DELTA2;
  float th3 = (t < 16) ? (fdec(gmin[t + 768]) + DELTA2) : -INFINITY;
  for (int g = g0; g < g1; ++g) {
    const float* col = partial + (size_t)g * MPAD;
    float v0 = col[t], v1 = col[t + 256], v2 = col[t + 512];
    float v3 = (t < 128) ? col[t + 768] : INFINITY;
    if (v0 <= th0) { unsigned p = atomicAdd(cnt, 1u); list[p] = ((unsigned)t << 12) | (unsigned)g; }
    if (v1 <= th1) { unsigned p = atomicAdd(cnt, 1u); list[p] = ((unsigned)(t + 256) << 12) | (unsigned)g; }
    if (v2 <= th2) { unsigned p = atomicAdd(cnt, 1u); list[p] = ((unsigned)(t + 512) << 12) | (unsigned)g; }
    if (t < 16 && v3 <= th3) { unsigned p = atomicAdd(cnt, 1u); list[p] = ((unsigned)(t + 768) << 12) | (unsigned)g; }
  }
}

// ===== exact fp32 rescore of candidate granules -> pmin (packed atomicMin) =====
__global__ __launch_bounds__(256) void k_rescore(const unsigned int* __restrict__ list,
                                                 const unsigned int* __restrict__ cnt,
                                                 const float* __restrict__ patch,
                                                 const float* __restrict__ lib,
                                                 const float* __restrict__ a2,
                                                 const float* __restrict__ b2,
                                                 unsigned long long* __restrict__ pmin) {
  int wid = (blockIdx.x << 2) | (threadIdx.x >> 6);
  int lane = threadIdx.x & 63;
  int n = (int)*cnt;
  for (int c = wid; c < n; c += RESCORE_WAVES) {
    unsigned int e = list[c];
    int i = (int)(e >> 12);
    int g = (int)(e & 4095u);
    int j = (g << 6) + lane;
    unsigned long long best = ~0ull;
    if (j < NL) {
      const float* pr = patch + (size_t)i * DIM;
      const float* lr = lib + (size_t)j * DIM;
      float d0 = 0.f, d1 = 0.f, d2s = 0.f, d3 = 0.f;
#pragma unroll 8
      for (int k = 0; k < DIM; k += 4) {
        float4 lv = *(const float4*)(lr + k);
        float4 pv = *(const float4*)(pr + k);
        d0 = fmaf(lv.x, pv.x, d0);
        d1 = fmaf(lv.y, pv.y, d1);
        d2s = fmaf(lv.z, pv.z, d2s);
        d3 = fmaf(lv.w, pv.w, d3);
      }
      float dot = (d0 + d1) + (d2s + d3);
      float d2 = fmaxf(a2[i] + b2[j] - 2.f * dot, 0.f);
      best = packdj(d2, j);
    }
#pragma unroll
    for (int mm = 1; mm < 64; mm <<= 1) {
      unsigned long long o = __shfl_xor(best, mm);
      best = (o < best) ? o : best;
    }
    if (lane == 0) atomicMin(pmin + i, best);
  }
}

// ===== fused finalize + resize: blocks 0..195 resize; block 196 computes s_star/s_idx =====
__global__ __launch_bounds__(256) void k_finres(const unsigned long long* __restrict__ pmin,
                                                float* __restrict__ scalf,
                                                int* __restrict__ scali,
                                                float* __restrict__ out) {
  int t = threadIdx.x;
  if (blockIdx.x < RESIZE_BLOCKS) {
    int o = blockIdx.x * 256 + t;
    int y = o / 224, x = o - y * 224;
    float sy = (y + 0.5f) * 0.125f - 0.5f;
    float sx = (x + 0.5f) * 0.125f - 0.5f;
    int y0 = (int)floorf(sy); float fy = sy - (float)y0;
    int x0 = (int)floorf(sx); float fx = sx - (float)x0;
    int y0c = max(y0, 0), y1c = min(y0 + 1, 27);
    int x0c = max(x0, 0), x1c = min(x0 + 1, 27);
#define MV(idx) sqrtf(__uint_as_float((unsigned int)(pmin[idx] >> 32)))
    float v00 = MV(y0c * 28 + x0c), v01 = MV(y0c * 28 + x1c);
    float v10 = MV(y1c * 28 + x0c), v11 = MV(y1c * 28 + x1c);
#undef MV
    float v0 = v00 + fx * (v01 - v00);
    float v1 = v10 + fx * (v11 - v10);
    out[1 + o] = v0 + fy * (v1 - v0);
  } else {
    __shared__ float sv[256];
    __shared__ int si[256];
    float bv = -1.f; int bi = 1 << 30;
    for (int i = t; i < NP; i += 256) {
      float v = sqrtf(__uint_as_float((unsigned int)(pmin[i] >> 32)));
      if (v > bv) { bv = v; bi = i; }
    }
    sv[t] = bv; si[t] = bi;
    __syncthreads();
    for (int s = 128; s > 0; s >>= 1) {
      if (t < s) {
        if (sv[t + s] > sv[t] || (sv[t + s] == sv[t] && si[t + s] < si[t])) {
          sv[t] = sv[t + s]; si[t] = si[t + s];
        }
      }
      __syncthreads();
    }
    if (t == 0) {
      scalf[0] = sv[0];
      scali[0] = si[0];
      scali[1] = (int)(unsigned int)(pmin[si[0]] & 0xFFFFFFFFull);
    }
  }
}

// ===== approx w_dist^2: contiguous per-wave chunks, 2-row unrolled [R14-verified] =====
__global__ __launch_bounds__(256) void k_wdist(const unsigned* __restrict__ Bq4,
                                               const float* __restrict__ b2,
                                               const int* __restrict__ scali,
                                               float* __restrict__ wd2,
                                               unsigned long long* __restrict__ top3w) {
  __shared__ unsigned long long sm[12];
  int wave = threadIdx.x >> 6, lane = threadIdx.x & 63;
  int jstar = scali[1];
  const unsigned* msrow = Bq4 + (size_t)jstar * 96;
  unsigned m0 = msrow[lane];
  unsigned m1 = (lane < 32) ? msrow[64 + lane] : 0u;
  float bstar = b2[jstar];
  unsigned long long t0 = ~0ull, t1 = ~0ull, t2 = ~0ull;
  int wid = (blockIdx.x << 2) | wave;
  int r0 = wid * WD_CHUNK;
  int rend = min(r0 + WD_CHUNK, NL);
  for (int j = r0; j + 1 < rend; j += 2) {
    const unsigned* rowa = Bq4 + (size_t)j * 96;
    const unsigned* rowb = rowa + 96;
    unsigned a0 = rowa[lane], b0 = rowb[lane];
    unsigned a1 = 0u, b1 = 0u;
    if (lane < 32) { a1 = rowa[64 + lane]; b1 = rowb[64 + lane]; }
    int ia = dot4acc(m0, a0, 0);
    int ib = dot4acc(m0, b0, 0);
    if (lane < 32) { ia = dot4acc(m1, a1, ia); ib = dot4acc(m1, b1, ib); }
#pragma unroll
    for (int mm = 1; mm < 64; mm <<= 1) {
      ia += __shfl_xor(ia, mm);
      ib += __shfl_xor(ib, mm);
    }
    float d2a = fmaxf(bstar + b2[j] - 2.f * S2 * (float)ia, 0.f);
    float d2b = fmaxf(bstar + b2[j + 1] - 2.f * S2 * (float)ib, 0.f);
    if (lane == 0) { wd2[j] = d2a; wd2[j + 1] = d2b; }
    ins3(t0, t1, t2, packdj(d2a, j));
    ins3(t0, t1, t2, packdj(d2b, j + 1));
  }
  if ((rend - r0) & 1) {
    int j = rend - 1;
    const unsigned* row = Bq4 + (size_t)j * 96;
    int id = dot4acc(m0, row[lane], 0);
    if (lane < 32) id = dot4acc(m1, row[64 + lane], id);
#pragma unroll
    for (int mm = 1; mm < 64; mm <<= 1) id += __shfl_xor(id, mm);
    float d2 = fmaxf(bstar + b2[j] - 2.f * S2 * (float)id, 0.f);
    if (lane == 0) wd2[j] = d2;
    ins3(t0, t1, t2, packdj(d2, j));
  }
  if (lane == 0) { sm[wave * 3] = t0; sm[wave * 3 + 1] = t1; sm[wave * 3 + 2] = t2; }
  __syncthreads();
  if (threadIdx.x == 0) {
    unsigned long long a0 = ~0ull, a1 = ~0ull, a2v = ~0ull;
    for (int e = 0; e < 12; ++e) ins3(a0, a1, a2v, sm[e]);
    top3w[blockIdx.x * 3 + 0] = a0;
    top3w[blockIdx.x * 3 + 1] = a1;
    top3w[blockIdx.x * 3 + 2] = a2v;
  }
}

// ===== merge approx top-3 -> threshold [verified R5/R12] =====
__global__ __launch_bounds__(256) void k_wsel1(const unsigned long long* __restrict__ top3w,
                                               float* __restrict__ scalf) {
  __shared__ unsigned long long sm[768];
  int t = threadIdx.x;
  unsigned long long t0 = ~0ull, t1 = ~0ull, t2 = ~0ull;
  for (int e = t; e < WTOP_BLOCKS * 3; e += 256) ins3(t0, t1, t2, top3w[e]);
  sm[t] = t0; sm[256 + t] = t1; sm[512 + t] = t2;
  __syncthreads();
  if (t == 0) {
    unsigned long long a0 = ~0ull, a1 = ~0ull, a2v = ~0ull;
    for (int e = 0; e < 768; ++e) ins3(a0, a1, a2v, sm[e]);
    scalf[1] = __uint_as_float((unsigned int)(a2v >> 32)) + DELTAW;
  }
}

// ===== collect all j with wd2 <= thr [verified R5] =====
__global__ __launch_bounds__(256) void k_wsel2(const float* __restrict__ wd2,
                                               const float* __restrict__ scalf,
                                               unsigned int* __restrict__ wlist,
                                               unsigned int* __restrict__ wcnt) {
  float thr = scalf[1];
  for (int j = blockIdx.x * 256 + threadIdx.x; j < NL; j += 256 * 256) {
    if (wd2[j] <= thr) {
      unsigned int pos = atomicAdd(wcnt, 1u);
      if (pos < WCAP) wlist[pos] = (unsigned int)j;
    }
  }
}

// ===== exact rescore of w candidates -> top-3 -> final s [verified R5] =====
__global__ __launch_bounds__(256) void k_finals2(const float* __restrict__ patch,
                                                 const float* __restrict__ lib,
                                                 const float* __restrict__ b2,
                                                 const unsigned int* __restrict__ wlist,
                                                 const unsigned int* __restrict__ wcnt,
                                                 const float* __restrict__ scalf,
                                                 const int* __restrict__ scali,
                                                 float* __restrict__ out) {
  __shared__ unsigned long long pk[WCAP];
  __shared__ int snn[2];
  __shared__ float sd[2];
  int t = threadIdx.x, wv = t >> 6, lane = t & 63;
  int n = min((int)*wcnt, WCAP);
  int jstar = scali[1];
  const float* mstar = lib + (size_t)jstar * DIM;
  float bstar = b2[jstar];
  for (int c = wv; c < n; c += 4) {
    int j = (int)wlist[c];
    const float* lr = lib + (size_t)j * DIM;
    float s = 0.f;
#pragma unroll
    for (int q = 0; q < 6; ++q)
      s = fmaf(mstar[lane + (q << 6)], lr[lane + (q << 6)], s);
#pragma unroll
    for (int mm = 1; mm < 64; mm <<= 1) s += __shfl_xor(s, mm);
    if (lane == 0) pk[c] = packdj(fmaxf(bstar + b2[j] - 2.f * s, 0.f), j);
  }
  __syncthreads();
  if (t == 0) {
    unsigned long long a0 = ~0ull, a1 = ~0ull, a2v = ~0ull;
    for (int e = 0; e < n; ++e) ins3(a0, a1, a2v, pk[e]);
    snn[0] = (int)(unsigned int)(a1 & 0xFFFFFFFFull);
    snn[1] = (int)(unsigned int)(a2v & 0xFFFFFFFFull);
  }
  __syncthreads();
  if (t < 128) {
    const float* mt = patch + (size_t)scali[0] * DIM;
    const float* bp = lib + (size_t)snn[wv] * DIM;
    float s = 0.f;
#pragma unroll
    for (int q = 0; q < 6; ++q) {
      float d = mt[lane + (q << 6)] - bp[lane + (q << 6)];
      s = fmaf(d, d, s);
    }
#pragma unroll
    for (int mm = 1; mm < 64; mm <<= 1) s += __shfl_xor(s, mm);
    if (lane == 0) sd[wv] = sqrtf(fmaxf(s, 0.f));
  }
  __syncthreads();
  if (t == 0) {
    const float Ds = 19.595917942265423f;  // sqrt(384)
    float sstar = scalf[0];
    float w = 1.f - expf(sstar / Ds) / (expf(sd[0] / Ds) + expf(sd[1] / Ds));
    out[0] = w * sstar;
  }
}

// ======= fallback fp32 path kernels (used only if ws_size is too small) =======
__global__ __launch_bounds__(256) void k_norms(const float* __restrict__ patch,
                                               const float* __restrict__ lib,
                                               float* __restrict__ a2,
                                               float* __restrict__ b2) {
  int wave = (blockIdx.x << 2) | (threadIdx.x >> 6);
  int lane = threadIdx.x & 63;
  const int NR = NL + NP;
  if (wave >= NR) return;
  const float* src = (wave < NL) ? (lib + (size_t)wave * DIM)
                                 : (patch + (size_t)(wave - NL) * DIM);
  float s = 0.f;
#pragma unroll
  for (int m = 0; m < 6; ++m) { float v = src[lane + (m << 6)]; s += v * v; }
#pragma unroll
  for (int m = 1; m < 64; m <<= 1) s += __shfl_xor(s, m);
  if (lane == 0) { if (wave < NL) b2[wave] = s; else a2[wave - NL] = s; }
}

__global__ __launch_bounds__(256) void k_distmin(const float* __restrict__ patch,
                                                 const float* __restrict__ lib,
                                                 const float* __restrict__ a2,
                                                 const float* __restrict__ b2,
                                                 unsigned long long* __restrict__ pmin) {
  __shared__ float As[16][68];
  __shared__ float Bs[16][68];
  const int t = threadIdx.x;
  const int lr = t >> 2;
  const int lc = (t & 3) << 2;
  const int ti = t >> 4;
  const int tj = t & 15;
  const int i0 = blockIdx.y << 6;
  const int j0 = blockIdx.x << 6;
  const bool a_ok = (i0 + lr) < NP;
  const float* ap = patch + (size_t)(i0 + lr) * DIM + lc;
  const float* bp = lib + (size_t)(j0 + lr) * DIM + lc;

  float acc[4][4] = {};
  for (int k0 = 0; k0 < DIM; k0 += 16) {
    float4 avv = make_float4(0.f, 0.f, 0.f, 0.f);
    if (a_ok) avv = *(const float4*)(ap + k0);
    float4 bvv = *(const float4*)(bp + k0);
    __syncthreads();
    As[lc + 0][lr] = avv.x; As[lc + 1][lr] = avv.y;
    As[lc + 2][lr] = avv.z; As[lc + 3][lr] = avv.w;
    Bs[lc + 0][lr] = bvv.x; Bs[lc + 1][lr] = bvv.y;
    Bs[lc + 2][lr] = bvv.z; Bs[lc + 3][lr] = bvv.w;
    __syncthreads();
#pragma unroll
    for (int kk = 0; kk < 16; ++kk) {
      float4 a = *(const float4*)&As[kk][ti << 2];
      float4 b = *(const float4*)&Bs[kk][tj << 2];
      acc[0][0] += a.x * b.x; acc[0][1] += a.x * b.y; acc[0][2] += a.x * b.z; acc[0][3] += a.x * b.w;
      acc[1][0] += a.y * b.x; acc[1][1] += a.y * b.y; acc[1][2] += a.y * b.z; acc[1][3] += a.y * b.w;
      acc[2][0] += a.z * b.x; acc[2][1] += a.z * b.y; acc[2][2] += a.z * b.z; acc[2][3] += a.z * b.w;
      acc[3][0] += a.w * b.x; acc[3][1] += a.w * b.y; acc[3][2] += a.w * b.z; acc[3][3] += a.w * b.w;
    }
  }
#pragma unroll
  for (int r = 0; r < 4; ++r) {
    int i = i0 + (ti << 2) + r;
    unsigned long long best = ~0ull;
    if (i < NP) {
      float ai = a2[i];
#pragma unroll
      for (int c = 0; c < 4; ++c) {
        int j = j0 + (tj << 2) + c;
        float d2 = fmaxf(ai + b2[j] - 2.f * acc[r][c], 0.f);
        unsigned long long p = packdj(d2, j);
        best = (p < best) ? p : best;
      }
    }
#pragma unroll
    for (int m = 1; m < 16; m <<= 1) {
      unsigned long long o = __shfl_xor(best, m);
      best = (o < best) ? o : best;
    }
    if (tj == 0 && i < NP) atomicMin(pmin + i, best);
  }
}

__global__ __launch_bounds__(256) void k_wtop(const float* __restrict__ lib,
                                              const int* __restrict__ scali,
                                              unsigned long long* __restrict__ top3) {
  __shared__ unsigned long long sm[12];
  int wave = threadIdx.x >> 6, lane = threadIdx.x & 63;
  int jstar = scali[1];
  const float* ms = lib + (size_t)jstar * DIM;
  float m[6];
#pragma unroll
  for (int q = 0; q < 6; ++q) m[q] = ms[lane + (q << 6)];
  unsigned long long t0 = ~0ull, t1 = ~0ull, t2 = ~0ull;
  int gw = (blockIdx.x << 2) | wave;
  for (int j = gw; j < NL; j += WTOP_BLOCKS * 4) {
    const float* bp = lib + (size_t)j * DIM;
    float s = 0.f;
#pragma unroll
    for (int q = 0; q < 6; ++q) { float d = bp[lane + (q << 6)] - m[q]; s += d * d; }
#pragma unroll
    for (int mm = 1; mm < 64; mm <<= 1) s += __shfl_xor(s, mm);
    ins3(t0, t1, t2, packdj(fmaxf(s, 0.f), j));
  }
  if (lane == 0) { sm[wave * 3] = t0; sm[wave * 3 + 1] = t1; sm[wave * 3 + 2] = t2; }
  __syncthreads();
  if (threadIdx.x == 0) {
    unsigned long long a0 = ~0ull, a1 = ~0ull, a2v = ~0ull;
    for (int e = 0; e < 12; ++e) ins3(a0, a1, a2v, sm[e]);
    top3[blockIdx.x * 3 + 0] = a0;
    top3[blockIdx.x * 3 + 1] = a1;
    top3[blockIdx.x * 3 + 2] = a2v;
  }
}

__global__ __launch_bounds__(256) void k_finals(const float* __restrict__ patch,
                                                const float* __restrict__ lib,
                                                const unsigned long long* __restrict__ top3,
                                                const float* __restrict__ scalf,
                                                const int* __restrict__ scali,
                                                float* __restrict__ out) {
  __shared__ unsigned long long sm[768];
  __shared__ int snn[2];
  __shared__ float sd[2];
  int t = threadIdx.x;
  unsigned long long t0 = ~0ull, t1 = ~0ull, t2 = ~0ull;
  for (int e = t; e < WTOP_BLOCKS * 3; e += 256) ins3(t0, t1, t2, top3[e]);
  sm[t] = t0; sm[256 + t] = t1; sm[512 + t] = t2;
  __syncthreads();
  if (t == 0) {
    unsigned long long a0 = ~0ull, a1 = ~0ull, a2v = ~0ull;
    for (int e = 0; e < 768; ++e) ins3(a0, a1, a2v, sm[e]);
    snn[0] = (int)(unsigned int)(a1 & 0xFFFFFFFFull);
    snn[1] = (int)(unsigned int)(a2v & 0xFFFFFFFFull);
  }
  __syncthreads();
  if (t < 128) {
    int wv = t >> 6, lane = t & 63;
    const float* mt = patch + (size_t)scali[0] * DIM;
    const float* bp = lib + (size_t)snn[wv] * DIM;
    float s = 0.f;
#pragma unroll
    for (int q = 0; q < 6; ++q) {
      float d = mt[lane + (q << 6)] - bp[lane + (q << 6)];
      s += d * d;
    }
#pragma unroll
    for (int mm = 1; mm < 64; mm <<= 1) s += __shfl_xor(s, mm);
    if (lane == 0) sd[wv] = sqrtf(fmaxf(s, 0.f));
  }
  __syncthreads();
  if (t == 0) {
    const float Ds = 19.595917942265423f;
    float sstar = scalf[0];
    float w = 1.f - expf(sstar / Ds) / (expf(sd[0] / Ds) + expf(sd[1] / Ds));
    out[0] = w * sstar;
  }
}

extern "C" void kernel_launch(void* const* d_in, const int* in_sizes, int n_in,
                              void* d_out, int out_size, void* d_ws, size_t ws_size,
                              hipStream_t stream) {
  const float* patch = (const float*)d_in[0];
  const float* lib = (const float*)d_in[1];
  float* out = (float*)d_out;
  char* ws = (char*)d_ws;

  const size_t SZ_BPLANE = (size_t)NLPAD * DIM;              // 76,824,576 (int8)
  const size_t SZ_APLANE = (size_t)MPAD * DIM;               // 344,064 (int8)
  const size_t SZ_PART = (size_t)PCOLS * MPAD * 4;           // 11,203,584
  const size_t SZ_LIST = (size_t)NP * PCOLS * 4;             // 9,803,136
  const size_t SZ_WD2 = (size_t)NLPAD * 4;                   // 800,256
  const size_t NEED = SZ_BPLANE + SZ_APLANE + SZ_PART + SZ_LIST + SZ_WD2 + 4 * 1024 * 1024;

  if (ws_size >= NEED) {
    size_t off = 0;
    unsigned char* Bq = (unsigned char*)(ws + off); off += SZ_BPLANE;
    unsigned char* Aq = (unsigned char*)(ws + off); off += SZ_APLANE;
    float* partial = (float*)(ws + off); off += SZ_PART;
    unsigned int* list = (unsigned int*)(ws + off); off += SZ_LIST;
    float* wd2 = (float*)(ws + off); off += SZ_WD2;
    float* b2 = (float*)(ws + off); off += (size_t)NLPAD * 4;
    float* a2 = (float*)(ws + off); off += (size_t)MPAD * 4;
    unsigned long long* pmin = (unsigned long long*)(ws + off); off += NP * 8;
    unsigned long long* top3w = (unsigned long long*)(ws + off); off += WTOP_BLOCKS * 3 * 8;
    unsigned int* wlist = (unsigned int*)(ws + off); off += WCAP * 4;
    unsigned int* gmin = (unsigned int*)(ws + off); off += MPAD * 4;
    float* scalf = (float*)(ws + off); off += 16;
    int* scali = (int*)(ws + off); off += 16;
    unsigned int* cnt = (unsigned int*)(ws + off); off += 32;  // [0]=cnt [1]=wcnt

    k_prep<<<PREP_GRID, 256, 0, stream>>>(lib, patch, (unsigned*)Bq, (unsigned*)Aq,
                                          b2, a2, pmin, cnt, gmin);
    k_gemm<<<MTILES * NTILES, 256, 0, stream>>>(Aq, Bq, b2, partial, gmin);
    k_select<<<SCAN_BLOCKS, 256, 0, stream>>>(partial, gmin, list, cnt);
    k_rescore<<<RESCORE_WAVES / 4, 256, 0, stream>>>(list, cnt, patch, lib, a2, b2, pmin);
    k_finres<<<RESIZE_BLOCKS + 1, 256, 0, stream>>>(pmin, scalf, scali, out);
    k_wdist<<<WTOP_BLOCKS, 256, 0, stream>>>((unsigned*)Bq, b2, scali, wd2, top3w);
    k_wsel1<<<1, 256, 0, stream>>>(top3w, scalf);
    k_wsel2<<<256, 256, 0, stream>>>(wd2, scalf, wlist, cnt + 1);
    k_finals2<<<1, 256, 0, stream>>>(patch, lib, b2, wlist, cnt + 1, scalf, scali, out);
  } else {
    // fallback: fp32 VALU path (verified R1)
    float* b2 = (float*)ws;
    float* a2 = (float*)(ws + 800000);
    unsigned long long* pmin = (unsigned long long*)(ws + 803200);
    unsigned long long* top3 = (unsigned long long*)(ws + 809472);
    float* scalf = (float*)(ws + 824896);
    int* scali = (int*)(ws + 824912);

    hipMemsetAsync(pmin, 0xFF, NP * sizeof(unsigned long long), stream);
    k_norms<<<(NL + NP + 3) / 4, 256, 0, stream>>>(patch, lib, a2, b2);
    dim3 grid(NL / 64, (NP + 63) / 64);
    k_distmin<<<grid, 256, 0, stream>>>(patch, lib, a2, b2, pmin);
    k_finres<<<RESIZE_BLOCKS + 1, 256, 0, stream>>>(pmin, scalf, scali, out);
    k_wtop<<<WTOP_BLOCKS, 256, 0, stream>>>(lib, scali, top3);
    k_finals<<<1, 256, 0, stream>>>(patch, lib, top3, scalf, scali, out);
  }
}

// Round 17
// 483.296 us; speedup vs baseline: 1.3375x; 1.3062x over previous
//
#include <hip/hip_runtime.h>

#define NP 784
#define DIM 384
#define NL 200000
#define WTOP_BLOCKS 512
#define WCAP 4096

#define BM 128
#define BN 128
#define BK 64
#define NSTEP 6
#define MTILES 7
#define NTILES 1563
#define MPAD (MTILES * BM)     // 896
#define NLPAD (NTILES * BN)    // 200064
#define PCOLS (NTILES * 2)     // 3126 granules of 64 j's per i
#define DELTA2 3.0f            // margin on approx val (i8 screen)
#define DELTAW 6.0f            // margin for w_dist top-3 selection
#define RESCORE_WAVES 2048

#define QS (6.5f / 127.0f)
#define QINV (127.0f / 6.5f)
#define NEG2S2 (-2.0f * QS * QS)
#define S2 (QS * QS)

#define PB_ROWS 96
#define PB_F4 (PB_ROWS * 96)       // 9216 float4 per block
#define PB_ITERS (PB_F4 / 256)     // 36
#define PB_GRID (NLPAD / PB_ROWS)  // 2084 (exact)
#define PREP_GRID (PB_GRID + MPAD / 4)  // 2308

#define SCAN_BLOCKS 96
#define GCHUNK ((PCOLS + SCAN_BLOCKS - 1) / SCAN_BLOCKS)  // 33

#define WD_WAVES (WTOP_BLOCKS * 4)                         // 2048
#define WD_CHUNK ((NL + WD_WAVES - 1) / WD_WAVES)          // 98

#define RESIZE_BLOCKS 196      // 196*256 = 50176 = 224*224

typedef __attribute__((ext_vector_type(4))) int int4v;

__device__ __forceinline__ unsigned long long packdj(float d2, int j) {
  return ((unsigned long long)__float_as_uint(d2) << 32) | (unsigned int)j;
}

__device__ __forceinline__ void ins3(unsigned long long &t0, unsigned long long &t1,
                                     unsigned long long &t2, unsigned long long p) {
  if (p < t0) { t2 = t1; t1 = t0; t0 = p; }
  else if (p < t1) { t2 = t1; t1 = p; }
  else if (p < t2) { t2 = p; }
}

// monotone f32 <-> u32 order-preserving encoding
__device__ __forceinline__ unsigned fenc(float x) {
  unsigned u = __float_as_uint(x);
  return (u & 0x80000000u) ? ~u : (u | 0x80000000u);
}
__device__ __forceinline__ float fdec(unsigned e) {
  unsigned u = (e & 0x80000000u) ? (e ^ 0x80000000u) : ~e;
  return __uint_as_float(u);
}

__device__ __forceinline__ int qclamp(float x) {
  int q = (int)rintf(x * QINV);
  return max(-127, min(127, q));
}
__device__ __forceinline__ unsigned qpack4(float4 v) {
  int q0 = qclamp(v.x), q1 = qclamp(v.y), q2 = qclamp(v.z), q3 = qclamp(v.w);
  return (unsigned)(q0 & 255) | ((unsigned)(q1 & 255) << 8) |
         ((unsigned)(q2 & 255) << 16) | ((unsigned)(q3 & 255) << 24);
}

#if __has_builtin(__builtin_amdgcn_sdot4)
__device__ __forceinline__ int dot4acc(unsigned a, unsigned b, int c) {
  return __builtin_amdgcn_sdot4((int)a, (int)b, c, false);
}
#else
__device__ __forceinline__ int dot4acc(unsigned a, unsigned b, int c) {
#pragma unroll
  for (int k = 0; k < 4; ++k)
    c += ((int)(signed char)((a >> (8 * k)) & 255)) *
         ((int)(signed char)((b >> (8 * k)) & 255));
  return c;
}
#endif
__device__ __forceinline__ int fxr(int row) { return (row ^ (row >> 2)) & 3; }

// ========== merged prep: blocks [0,PB_GRID) quantize lib; rest quantize patch ==========
__global__ __launch_bounds__(256) void k_prep(const float* __restrict__ lib,
                                              const float* __restrict__ patch,
                                              unsigned* __restrict__ Bq4,
                                              unsigned* __restrict__ Aq4,
                                              float* __restrict__ b2,
                                              float* __restrict__ a2,
                                              unsigned long long* __restrict__ pmin,
                                              unsigned int* __restrict__ cnt,
                                              unsigned int* __restrict__ gmin) {
  const int t = threadIdx.x;
  if (blockIdx.x < PB_GRID) {
    __shared__ float rs[PB_ROWS][2];
    const int w = t >> 6, lane = t & 63;
    const size_t gbase = (size_t)blockIdx.x * PB_F4;
    const int rbase = blockIdx.x * PB_ROWS;
    const float4* lib4 = (const float4*)lib;
    const size_t NF4REAL = (size_t)NL * 96;

    for (int it = 0; it < PB_ITERS; ++it) {
      int fl = it * 256 + t;
      size_t f = gbase + fl;
      float4 v = make_float4(0.f, 0.f, 0.f, 0.f);
      if (f < NF4REAL) v = lib4[f];
      float sum = fmaf(v.x, v.x, fmaf(v.y, v.y, fmaf(v.z, v.z, v.w * v.w)));
      Bq4[f] = qpack4(v);

      int wstart = it * 256 + (w << 6);
      int r0 = wstart / 96;
      int s = (r0 + 1) * 96 - wstart;          // in {32, 64, 96}
      float lo = (lane < s) ? sum : 0.f;
#pragma unroll
      for (int m = 1; m < 64; m <<= 1) lo += __shfl_xor(lo, m);
      if (lane == 0) rs[r0][(s == 96) ? 0 : 1] = lo;
      if (s == 32) {
        float hi = (lane >= 32) ? sum : 0.f;
#pragma unroll
        for (int m = 1; m < 64; m <<= 1) hi += __shfl_xor(hi, m);
        if (lane == 0) rs[r0 + 1][0] = hi;
      }
    }
    __syncthreads();
    if (t < PB_ROWS) {
      int r = rbase + t;
      b2[r] = (r < NL) ? (rs[t][0] + rs[t][1]) : INFINITY;
    }
  } else {
    int ab = blockIdx.x - PB_GRID;
    if (ab == 0) {
      for (int q = t; q < NP; q += 256) pmin[q] = ~0ull;
      for (int q = t; q < MPAD; q += 256) gmin[q] = 0xFFFFFFFFu;
      if (t < 8) cnt[t] = 0;
    }
    int i = (ab << 2) | (t >> 6);
    int lane = t & 63;
    if (i >= MPAD) return;
    unsigned* orow = Aq4 + (size_t)i * 96;
    if (i < NP) {
      const float4* r4 = (const float4*)(patch + (size_t)i * DIM);
      float s = 0.f;
      float4 v = r4[lane];
      s = fmaf(v.x, v.x, fmaf(v.y, v.y, fmaf(v.z, v.z, fmaf(v.w, v.w, s))));
      orow[lane] = qpack4(v);
      if (lane < 32) {
        float4 v1 = r4[64 + lane];
        s = fmaf(v1.x, v1.x, fmaf(v1.y, v1.y, fmaf(v1.z, v1.z, fmaf(v1.w, v1.w, s))));
        orow[64 + lane] = qpack4(v1);
      }
#pragma unroll
      for (int m = 1; m < 64; m <<= 1) s += __shfl_xor(s, m);
      if (lane == 0) a2[i] = s;
    } else {
      orow[lane] = 0u;
      if (lane < 32) orow[64 + lane] = 0u;
    }
  }
}

// ====== main: 128x128 i8 MFMA GEMM, BK=64, dbuf 2-phase prefetch [R12/R14-verified] ======
// NO gmin atomics here (R15/R16 regression: 2.8M contended cross-XCD atomicMin ops).
__global__ __launch_bounds__(256, 4) void k_gemm(const unsigned char* __restrict__ Aq,
                                                 const unsigned char* __restrict__ Bq,
                                                 const float* __restrict__ b2,
                                                 float* __restrict__ partial) {
  __shared__ char sA[16384], sB[16384];   // 2 x 8KB each, 32KB total

  const int TOT = MTILES * NTILES;        // 10941
  const int q8 = TOT >> 3, r8 = TOT & 7;  // 1367, 5
  int xcd = blockIdx.x & 7, seq = blockIdx.x >> 3;
  int wg = (xcd < r8 ? xcd * (q8 + 1) : r8 * (q8 + 1) + (xcd - r8) * q8) + seq;
  int ntile = wg / MTILES;
  int mtile = wg - ntile * MTILES;
  const int i0 = mtile * BM;
  const int j0 = ntile * BN;

  const int t = threadIdx.x;
  const int w = t >> 6, lane = t & 63;
  const int wr = w >> 1, wc = w & 1;        // wave -> 64x64 sub-tile
  const int lrow = lane & 15, lk = lane >> 4;

  const char* srcs[4];
  int dslot[4];
  {
    int s0 = t, s1 = 256 + t;
    int r0 = s0 >> 2, c0 = (s0 & 3) ^ fxr(r0);
    int r1 = s1 >> 2, c1 = (s1 & 3) ^ fxr(r1);
    srcs[0] = (const char*)Aq + (size_t)(i0 + r0) * DIM + (c0 << 4);
    srcs[1] = (const char*)Aq + (size_t)(i0 + r1) * DIM + (c1 << 4);
    srcs[2] = (const char*)Bq + (size_t)(j0 + r0) * DIM + (c0 << 4);
    srcs[3] = (const char*)Bq + (size_t)(j0 + r1) * DIM + (c1 << 4);
    dslot[0] = s0 << 4; dslot[1] = s1 << 4;
    dslot[2] = s0 << 4; dslot[3] = s1 << 4;
  }

  int aoffs[4], boffs[4];
#pragma unroll
  for (int m = 0; m < 4; ++m) {
    int Ra = (wr << 6) + (m << 4) + lrow;
    aoffs[m] = (Ra << 6) + ((lk ^ fxr(Ra)) << 4);
    int Rb = (wc << 6) + (m << 4) + lrow;
    boffs[m] = (Rb << 6) + ((lk ^ fxr(Rb)) << 4);
  }

  int4v acc[4][4];
#pragma unroll
  for (int m = 0; m < 4; ++m)
#pragma unroll
    for (int n = 0; n < 4; ++n) acc[m][n] = (int4v){0, 0, 0, 0};

  __builtin_amdgcn_global_load_lds((const __attribute__((address_space(1))) void*)srcs[0],
                                   (__attribute__((address_space(3))) void*)(sA + dslot[0]), 16, 0, 0);
  __builtin_amdgcn_global_load_lds((const __attribute__((address_space(1))) void*)srcs[1],
                                   (__attribute__((address_space(3))) void*)(sA + dslot[1]), 16, 0, 0);
  __builtin_amdgcn_global_load_lds((const __attribute__((address_space(1))) void*)srcs[2],
                                   (__attribute__((address_space(3))) void*)(sB + dslot[2]), 16, 0, 0);
  __builtin_amdgcn_global_load_lds((const __attribute__((address_space(1))) void*)srcs[3],
                                   (__attribute__((address_space(3))) void*)(sB + dslot[3]), 16, 0, 0);
  __syncthreads();

#pragma unroll
  for (int step = 0; step < NSTEP; ++step) {
    const int cur = step & 1;
    const int curoff = cur << 13;
    if (step < NSTEP - 1) {
      const int nxtoff = (cur ^ 1) << 13;
      const int kb = (step + 1) << 6;
      __builtin_amdgcn_global_load_lds((const __attribute__((address_space(1))) void*)(srcs[0] + kb),
                                       (__attribute__((address_space(3))) void*)(sA + nxtoff + dslot[0]), 16, 0, 0);
      __builtin_amdgcn_global_load_lds((const __attribute__((address_space(1))) void*)(srcs[1] + kb),
                                       (__attribute__((address_space(3))) void*)(sA + nxtoff + dslot[1]), 16, 0, 0);
      __builtin_amdgcn_global_load_lds((const __attribute__((address_space(1))) void*)(srcs[2] + kb),
                                       (__attribute__((address_space(3))) void*)(sB + nxtoff + dslot[2]), 16, 0, 0);
      __builtin_amdgcn_global_load_lds((const __attribute__((address_space(1))) void*)(srcs[3] + kb),
                                       (__attribute__((address_space(3))) void*)(sB + nxtoff + dslot[3]), 16, 0, 0);
    }
    int4v fa[4], fb[4];
#pragma unroll
    for (int m = 0; m < 4; ++m) fa[m] = *(const int4v*)(sA + curoff + aoffs[m]);
#pragma unroll
    for (int n = 0; n < 4; ++n) fb[n] = *(const int4v*)(sB + curoff + boffs[n]);
#pragma unroll
    for (int m = 0; m < 4; ++m)
#pragma unroll
      for (int n = 0; n < 4; ++n)
        acc[m][n] = __builtin_amdgcn_mfma_i32_16x16x64_i8(fa[m], fb[n], acc[m][n], 0, 0, 0);
    if (step < NSTEP - 1) __syncthreads();
  }

  float b2v[4];
#pragma unroll
  for (int n = 0; n < 4; ++n) b2v[n] = b2[j0 + (wc << 6) + (n << 4) + lrow];
  const int gcol = (ntile << 1) + wc;
  float* pcol = partial + (size_t)gcol * MPAD;
#pragma unroll
  for (int m = 0; m < 4; ++m) {
    float4 v;
#pragma unroll
    for (int r = 0; r < 4; ++r) {
      float dm = INFINITY;
#pragma unroll
      for (int n = 0; n < 4; ++n)
        dm = fminf(dm, fmaf(NEG2S2, (float)acc[m][n][r], b2v[n]));
#pragma unroll
      for (int mm = 1; mm < 16; mm <<= 1)
        dm = fminf(dm, __shfl_xor(dm, mm));
      ((float*)&v)[r] = dm;
    }
    if (lrow == 0)
      *(float4*)(pcol + i0 + (wr << 6) + (m << 4) + (lk << 2)) = v;
  }
}

// ===== column min over gcols (coalesced): per-i global min via encoded atomicMin =====
__global__ __launch_bounds__(256) void k_colmin(const float* __restrict__ partial,
                                                unsigned int* __restrict__ gmin) {
  int t = threadIdx.x;
  int g0 = blockIdx.x * GCHUNK;
  int g1 = min(g0 + GCHUNK, PCOLS);
  float mv0 = INFINITY, mv1 = INFINITY, mv2 = INFINITY, mv3 = INFINITY;
  for (int g = g0; g < g1; ++g) {
    const float* col = partial + (size_t)g * MPAD;
    mv0 = fminf(mv0, col[t]);
    mv1 = fminf(mv1, col[t + 256]);
    mv2 = fminf(mv2, col[t + 512]);
    if (t < 128) mv3 = fminf(mv3, col[t + 768]);
  }
  atomicMin(&gmin[t], fenc(mv0));
  atomicMin(&gmin[t + 256], fenc(mv1));
  atomicMin(&gmin[t + 512], fenc(mv2));
  if (t < 128) atomicMin(&gmin[t + 768], fenc(mv3));
}

// ===== select candidates within margin (coalesced read) -> compacted list =====
__global__ __launch_bounds__(256) void k_select(const float* __restrict__ partial,
                                                const unsigned int* __restrict__ gmin,
                                                unsigned int* __restrict__ list,
                                                unsigned int* __restrict__ cnt) {
  int t = threadIdx.x;
  int g0 = blockIdx.x * GCHUNK;
  int g1 = min(g0 + GCHUNK, PCOLS);
  float th0 = fdec(gmin[t]) + DELTA2;
  float th1 = fdec(gmin[t + 256]) + DELTA2;
  float th2 = fdec(gmin[t + 512]) + DELTA2;
  float th3 = (t < 16) ? (fdec(gmin[t + 768]) + DELTA2) : -INFINITY;
  for (int g = g0; g < g1; ++g) {
    const float* col = partial + (size_t)g * MPAD;
    float v0 = col[t], v1 = col[t + 256], v2 = col[t + 512];
    float v3 = (t < 128) ? col[t + 768] : INFINITY;
    if (v0 <= th0) { unsigned p = atomicAdd(cnt, 1u); list[p] = ((unsigned)t << 12) | (unsigned)g; }
    if (v1 <= th1) { unsigned p = atomicAdd(cnt, 1u); list[p] = ((unsigned)(t + 256) << 12) | (unsigned)g; }
    if (v2 <= th2) { unsigned p = atomicAdd(cnt, 1u); list[p] = ((unsigned)(t + 512) << 12) | (unsigned)g; }
    if (t < 16 && v3 <= th3) { unsigned p = atomicAdd(cnt, 1u); list[p] = ((unsigned)(t + 768) << 12) | (unsigned)g; }
  }
}

// ===== exact fp32 rescore of candidate granules -> pmin (packed atomicMin) =====
__global__ __launch_bounds__(256) void k_rescore(const unsigned int* __restrict__ list,
                                                 const unsigned int* __restrict__ cnt,
                                                 const float* __restrict__ patch,
                                                 const float* __restrict__ lib,
                                                 const float* __restrict__ a2,
                                                 const float* __restrict__ b2,
                                                 unsigned long long* __restrict__ pmin) {
  int wid = (blockIdx.x << 2) | (threadIdx.x >> 6);
  int lane = threadIdx.x & 63;
  int n = (int)*cnt;
  for (int c = wid; c < n; c += RESCORE_WAVES) {
    unsigned int e = list[c];
    int i = (int)(e >> 12);
    int g = (int)(e & 4095u);
    int j = (g << 6) + lane;
    unsigned long long best = ~0ull;
    if (j < NL) {
      const float* pr = patch + (size_t)i * DIM;
      const float* lr = lib + (size_t)j * DIM;
      float d0 = 0.f, d1 = 0.f, d2s = 0.f, d3 = 0.f;
#pragma unroll 8
      for (int k = 0; k < DIM; k += 4) {
        float4 lv = *(const float4*)(lr + k);
        float4 pv = *(const float4*)(pr + k);
        d0 = fmaf(lv.x, pv.x, d0);
        d1 = fmaf(lv.y, pv.y, d1);
        d2s = fmaf(lv.z, pv.z, d2s);
        d3 = fmaf(lv.w, pv.w, d3);
      }
      float dot = (d0 + d1) + (d2s + d3);
      float d2 = fmaxf(a2[i] + b2[j] - 2.f * dot, 0.f);
      best = packdj(d2, j);
    }
#pragma unroll
    for (int mm = 1; mm < 64; mm <<= 1) {
      unsigned long long o = __shfl_xor(best, mm);
      best = (o < best) ? o : best;
    }
    if (lane == 0) atomicMin(pmin + i, best);
  }
}

// ===== fused finalize + resize: blocks 0..195 resize; block 196 computes s_star/s_idx =====
__global__ __launch_bounds__(256) void k_finres(const unsigned long long* __restrict__ pmin,
                                                float* __restrict__ scalf,
                                                int* __restrict__ scali,
                                                float* __restrict__ out) {
  int t = threadIdx.x;
  if (blockIdx.x < RESIZE_BLOCKS) {
    int o = blockIdx.x * 256 + t;
    int y = o / 224, x = o - y * 224;
    float sy = (y + 0.5f) * 0.125f - 0.5f;
    float sx = (x + 0.5f) * 0.125f - 0.5f;
    int y0 = (int)floorf(sy); float fy = sy - (float)y0;
    int x0 = (int)floorf(sx); float fx = sx - (float)x0;
    int y0c = max(y0, 0), y1c = min(y0 + 1, 27);
    int x0c = max(x0, 0), x1c = min(x0 + 1, 27);
#define MV(idx) sqrtf(__uint_as_float((unsigned int)(pmin[idx] >> 32)))
    float v00 = MV(y0c * 28 + x0c), v01 = MV(y0c * 28 + x1c);
    float v10 = MV(y1c * 28 + x0c), v11 = MV(y1c * 28 + x1c);
#undef MV
    float v0 = v00 + fx * (v01 - v00);
    float v1 = v10 + fx * (v11 - v10);
    out[1 + o] = v0 + fy * (v1 - v0);
  } else {
    __shared__ float sv[256];
    __shared__ int si[256];
    float bv = -1.f; int bi = 1 << 30;
    for (int i = t; i < NP; i += 256) {
      float v = sqrtf(__uint_as_float((unsigned int)(pmin[i] >> 32)));
      if (v > bv) { bv = v; bi = i; }
    }
    sv[t] = bv; si[t] = bi;
    __syncthreads();
    for (int s = 128; s > 0; s >>= 1) {
      if (t < s) {
        if (sv[t + s] > sv[t] || (sv[t + s] == sv[t] && si[t + s] < si[t])) {
          sv[t] = sv[t + s]; si[t] = si[t + s];
        }
      }
      __syncthreads();
    }
    if (t == 0) {
      scalf[0] = sv[0];
      scali[0] = si[0];
      scali[1] = (int)(unsigned int)(pmin[si[0]] & 0xFFFFFFFFull);
    }
  }
}

// ===== approx w_dist^2: contiguous per-wave chunks, 2-row unrolled [R14-verified] =====
__global__ __launch_bounds__(256) void k_wdist(const unsigned* __restrict__ Bq4,
                                               const float* __restrict__ b2,
                                               const int* __restrict__ scali,
                                               float* __restrict__ wd2,
                                               unsigned long long* __restrict__ top3w) {
  __shared__ unsigned long long sm[12];
  int wave = threadIdx.x >> 6, lane = threadIdx.x & 63;
  int jstar = scali[1];
  const unsigned* msrow = Bq4 + (size_t)jstar * 96;
  unsigned m0 = msrow[lane];
  unsigned m1 = (lane < 32) ? msrow[64 + lane] : 0u;
  float bstar = b2[jstar];
  unsigned long long t0 = ~0ull, t1 = ~0ull, t2 = ~0ull;
  int wid = (blockIdx.x << 2) | wave;
  int r0 = wid * WD_CHUNK;
  int rend = min(r0 + WD_CHUNK, NL);
  for (int j = r0; j + 1 < rend; j += 2) {
    const unsigned* rowa = Bq4 + (size_t)j * 96;
    const unsigned* rowb = rowa + 96;
    unsigned a0 = rowa[lane], b0 = rowb[lane];
    unsigned a1 = 0u, b1 = 0u;
    if (lane < 32) { a1 = rowa[64 + lane]; b1 = rowb[64 + lane]; }
    int ia = dot4acc(m0, a0, 0);
    int ib = dot4acc(m0, b0, 0);
    if (lane < 32) { ia = dot4acc(m1, a1, ia); ib = dot4acc(m1, b1, ib); }
#pragma unroll
    for (int mm = 1; mm < 64; mm <<= 1) {
      ia += __shfl_xor(ia, mm);
      ib += __shfl_xor(ib, mm);
    }
    float d2a = fmaxf(bstar + b2[j] - 2.f * S2 * (float)ia, 0.f);
    float d2b = fmaxf(bstar + b2[j + 1] - 2.f * S2 * (float)ib, 0.f);
    if (lane == 0) { wd2[j] = d2a; wd2[j + 1] = d2b; }
    ins3(t0, t1, t2, packdj(d2a, j));
    ins3(t0, t1, t2, packdj(d2b, j + 1));
  }
  if ((rend - r0) & 1) {
    int j = rend - 1;
    const unsigned* row = Bq4 + (size_t)j * 96;
    int id = dot4acc(m0, row[lane], 0);
    if (lane < 32) id = dot4acc(m1, row[64 + lane], id);
#pragma unroll
    for (int mm = 1; mm < 64; mm <<= 1) id += __shfl_xor(id, mm);
    float d2 = fmaxf(bstar + b2[j] - 2.f * S2 * (float)id, 0.f);
    if (lane == 0) wd2[j] = d2;
    ins3(t0, t1, t2, packdj(d2, j));
  }
  if (lane == 0) { sm[wave * 3] = t0; sm[wave * 3 + 1] = t1; sm[wave * 3 + 2] = t2; }
  __syncthreads();
  if (threadIdx.x == 0) {
    unsigned long long a0 = ~0ull, a1 = ~0ull, a2v = ~0ull;
    for (int e = 0; e < 12; ++e) ins3(a0, a1, a2v, sm[e]);
    top3w[blockIdx.x * 3 + 0] = a0;
    top3w[blockIdx.x * 3 + 1] = a1;
    top3w[blockIdx.x * 3 + 2] = a2v;
  }
}

// ===== merge approx top-3 -> threshold [verified R5/R12] =====
__global__ __launch_bounds__(256) void k_wsel1(const unsigned long long* __restrict__ top3w,
                                               float* __restrict__ scalf) {
  __shared__ unsigned long long sm[768];
  int t = threadIdx.x;
  unsigned long long t0 = ~0ull, t1 = ~0ull, t2 = ~0ull;
  for (int e = t; e < WTOP_BLOCKS * 3; e += 256) ins3(t0, t1, t2, top3w[e]);
  sm[t] = t0; sm[256 + t] = t1; sm[512 + t] = t2;
  __syncthreads();
  if (t == 0) {
    unsigned long long a0 = ~0ull, a1 = ~0ull, a2v = ~0ull;
    for (int e = 0; e < 768; ++e) ins3(a0, a1, a2v, sm[e]);
    scalf[1] = __uint_as_float((unsigned int)(a2v >> 32)) + DELTAW;
  }
}

// ===== collect all j with wd2 <= thr [verified R5] =====
__global__ __launch_bounds__(256) void k_wsel2(const float* __restrict__ wd2,
                                               const float* __restrict__ scalf,
                                               unsigned int* __restrict__ wlist,
                                               unsigned int* __restrict__ wcnt) {
  float thr = scalf[1];
  for (int j = blockIdx.x * 256 + threadIdx.x; j < NL; j += 256 * 256) {
    if (wd2[j] <= thr) {
      unsigned int pos = atomicAdd(wcnt, 1u);
      if (pos < WCAP) wlist[pos] = (unsigned int)j;
    }
  }
}

// ===== exact rescore of w candidates -> top-3 -> final s [verified R5] =====
__global__ __launch_bounds__(256) void k_finals2(const float* __restrict__ patch,
                                                 const float* __restrict__ lib,
                                                 const float* __restrict__ b2,
                                                 const unsigned int* __restrict__ wlist,
                                                 const unsigned int* __restrict__ wcnt,
                                                 const float* __restrict__ scalf,
                                                 const int* __restrict__ scali,
                                                 float* __restrict__ out) {
  __shared__ unsigned long long pk[WCAP];
  __shared__ int snn[2];
  __shared__ float sd[2];
  int t = threadIdx.x, wv = t >> 6, lane = t & 63;
  int n = min((int)*wcnt, WCAP);
  int jstar = scali[1];
  const float* mstar = lib + (size_t)jstar * DIM;
  float bstar = b2[jstar];
  for (int c = wv; c < n; c += 4) {
    int j = (int)wlist[c];
    const float* lr = lib + (size_t)j * DIM;
    float s = 0.f;
#pragma unroll
    for (int q = 0; q < 6; ++q)
      s = fmaf(mstar[lane + (q << 6)], lr[lane + (q << 6)], s);
#pragma unroll
    for (int mm = 1; mm < 64; mm <<= 1) s += __shfl_xor(s, mm);
    if (lane == 0) pk[c] = packdj(fmaxf(bstar + b2[j] - 2.f * s, 0.f), j);
  }
  __syncthreads();
  if (t == 0) {
    unsigned long long a0 = ~0ull, a1 = ~0ull, a2v = ~0ull;
    for (int e = 0; e < n; ++e) ins3(a0, a1, a2v, pk[e]);
    snn[0] = (int)(unsigned int)(a1 & 0xFFFFFFFFull);
    snn[1] = (int)(unsigned int)(a2v & 0xFFFFFFFFull);
  }
  __syncthreads();
  if (t < 128) {
    const float* mt = patch + (size_t)scali[0] * DIM;
    const float* bp = lib + (size_t)snn[wv] * DIM;
    float s = 0.f;
#pragma unroll
    for (int q = 0; q < 6; ++q) {
      float d = mt[lane + (q << 6)] - bp[lane + (q << 6)];
      s = fmaf(d, d, s);
    }
#pragma unroll
    for (int mm = 1; mm < 64; mm <<= 1) s += __shfl_xor(s, mm);
    if (lane == 0) sd[wv] = sqrtf(fmaxf(s, 0.f));
  }
  __syncthreads();
  if (t == 0) {
    const float Ds = 19.595917942265423f;  // sqrt(384)
    float sstar = scalf[0];
    float w = 1.f - expf(sstar / Ds) / (expf(sd[0] / Ds) + expf(sd[1] / Ds));
    out[0] = w * sstar;
  }
}

// ======= fallback fp32 path kernels (used only if ws_size is too small) =======
__global__ __launch_bounds__(256) void k_norms(const float* __restrict__ patch,
                                               const float* __restrict__ lib,
                                               float* __restrict__ a2,
                                               float* __restrict__ b2) {
  int wave = (blockIdx.x << 2) | (threadIdx.x >> 6);
  int lane = threadIdx.x & 63;
  const int NR = NL + NP;
  if (wave >= NR) return;
  const float* src = (wave < NL) ? (lib + (size_t)wave * DIM)
                                 : (patch + (size_t)(wave - NL) * DIM);
  float s = 0.f;
#pragma unroll
  for (int m = 0; m < 6; ++m) { float v = src[lane + (m << 6)]; s += v * v; }
#pragma unroll
  for (int m = 1; m < 64; m <<= 1) s += __shfl_xor(s, m);
  if (lane == 0) { if (wave < NL) b2[wave] = s; else a2[wave - NL] = s; }
}

__global__ __launch_bounds__(256) void k_distmin(const float* __restrict__ patch,
                                                 const float* __restrict__ lib,
                                                 const float* __restrict__ a2,
                                                 const float* __restrict__ b2,
                                                 unsigned long long* __restrict__ pmin) {
  __shared__ float As[16][68];
  __shared__ float Bs[16][68];
  const int t = threadIdx.x;
  const int lr = t >> 2;
  const int lc = (t & 3) << 2;
  const int ti = t >> 4;
  const int tj = t & 15;
  const int i0 = blockIdx.y << 6;
  const int j0 = blockIdx.x << 6;
  const bool a_ok = (i0 + lr) < NP;
  const float* ap = patch + (size_t)(i0 + lr) * DIM + lc;
  const float* bp = lib + (size_t)(j0 + lr) * DIM + lc;

  float acc[4][4] = {};
  for (int k0 = 0; k0 < DIM; k0 += 16) {
    float4 avv = make_float4(0.f, 0.f, 0.f, 0.f);
    if (a_ok) avv = *(const float4*)(ap + k0);
    float4 bvv = *(const float4*)(bp + k0);
    __syncthreads();
    As[lc + 0][lr] = avv.x; As[lc + 1][lr] = avv.y;
    As[lc + 2][lr] = avv.z; As[lc + 3][lr] = avv.w;
    Bs[lc + 0][lr] = bvv.x; Bs[lc + 1][lr] = bvv.y;
    Bs[lc + 2][lr] = bvv.z; Bs[lc + 3][lr] = bvv.w;
    __syncthreads();
#pragma unroll
    for (int kk = 0; kk < 16; ++kk) {
      float4 a = *(const float4*)&As[kk][ti << 2];
      float4 b = *(const float4*)&Bs[kk][tj << 2];
      acc[0][0] += a.x * b.x; acc[0][1] += a.x * b.y; acc[0][2] += a.x * b.z; acc[0][3] += a.x * b.w;
      acc[1][0] += a.y * b.x; acc[1][1] += a.y * b.y; acc[1][2] += a.y * b.z; acc[1][3] += a.y * b.w;
      acc[2][0] += a.z * b.x; acc[2][1] += a.z * b.y; acc[2][2] += a.z * b.z; acc[2][3] += a.z * b.w;
      acc[3][0] += a.w * b.x; acc[3][1] += a.w * b.y; acc[3][2] += a.w * b.z; acc[3][3] += a.w * b.w;
    }
  }
#pragma unroll
  for (int r = 0; r < 4; ++r) {
    int i = i0 + (ti << 2) + r;
    unsigned long long best = ~0ull;
    if (i < NP) {
      float ai = a2[i];
#pragma unroll
      for (int c = 0; c < 4; ++c) {
        int j = j0 + (tj << 2) + c;
        float d2 = fmaxf(ai + b2[j] - 2.f * acc[r][c], 0.f);
        unsigned long long p = packdj(d2, j);
        best = (p < best) ? p : best;
      }
    }
#pragma unroll
    for (int m = 1; m < 16; m <<= 1) {
      unsigned long long o = __shfl_xor(best, m);
      best = (o < best) ? o : best;
    }
    if (tj == 0 && i < NP) atomicMin(pmin + i, best);
  }
}

__global__ __launch_bounds__(256) void k_wtop(const float* __restrict__ lib,
                                              const int* __restrict__ scali,
                                              unsigned long long* __restrict__ top3) {
  __shared__ unsigned long long sm[12];
  int wave = threadIdx.x >> 6, lane = threadIdx.x & 63;
  int jstar = scali[1];
  const float* ms = lib + (size_t)jstar * DIM;
  float m[6];
#pragma unroll
  for (int q = 0; q < 6; ++q) m[q] = ms[lane + (q << 6)];
  unsigned long long t0 = ~0ull, t1 = ~0ull, t2 = ~0ull;
  int gw = (blockIdx.x << 2) | wave;
  for (int j = gw; j < NL; j += WTOP_BLOCKS * 4) {
    const float* bp = lib + (size_t)j * DIM;
    float s = 0.f;
#pragma unroll
    for (int q = 0; q < 6; ++q) { float d = bp[lane + (q << 6)] - m[q]; s += d * d; }
#pragma unroll
    for (int mm = 1; mm < 64; mm <<= 1) s += __shfl_xor(s, mm);
    ins3(t0, t1, t2, packdj(fmaxf(s, 0.f), j));
  }
  if (lane == 0) { sm[wave * 3] = t0; sm[wave * 3 + 1] = t1; sm[wave * 3 + 2] = t2; }
  __syncthreads();
  if (threadIdx.x == 0) {
    unsigned long long a0 = ~0ull, a1 = ~0ull, a2v = ~0ull;
    for (int e = 0; e < 12; ++e) ins3(a0, a1, a2v, sm[e]);
    top3[blockIdx.x * 3 + 0] = a0;
    top3[blockIdx.x * 3 + 1] = a1;
    top3[blockIdx.x * 3 + 2] = a2v;
  }
}

__global__ __launch_bounds__(256) void k_finals(const float* __restrict__ patch,
                                                const float* __restrict__ lib,
                                                const unsigned long long* __restrict__ top3,
                                                const float* __restrict__ scalf,
                                                const int* __restrict__ scali,
                                                float* __restrict__ out) {
  __shared__ unsigned long long sm[768];
  __shared__ int snn[2];
  __shared__ float sd[2];
  int t = threadIdx.x;
  unsigned long long t0 = ~0ull, t1 = ~0ull, t2 = ~0ull;
  for (int e = t; e < WTOP_BLOCKS * 3; e += 256) ins3(t0, t1, t2, top3[e]);
  sm[t] = t0; sm[256 + t] = t1; sm[512 + t] = t2;
  __syncthreads();
  if (t == 0) {
    unsigned long long a0 = ~0ull, a1 = ~0ull, a2v = ~0ull;
    for (int e = 0; e < 768; ++e) ins3(a0, a1, a2v, sm[e]);
    snn[0] = (int)(unsigned int)(a1 & 0xFFFFFFFFull);
    snn[1] = (int)(unsigned int)(a2v & 0xFFFFFFFFull);
  }
  __syncthreads();
  if (t < 128) {
    int wv = t >> 6, lane = t & 63;
    const float* mt = patch + (size_t)scali[0] * DIM;
    const float* bp = lib + (size_t)snn[wv] * DIM;
    float s = 0.f;
#pragma unroll
    for (int q = 0; q < 6; ++q) {
      float d = mt[lane + (q << 6)] - bp[lane + (q << 6)];
      s += d * d;
    }
#pragma unroll
    for (int mm = 1; mm < 64; mm <<= 1) s += __shfl_xor(s, mm);
    if (lane == 0) sd[wv] = sqrtf(fmaxf(s, 0.f));
  }
  __syncthreads();
  if (t == 0) {
    const float Ds = 19.595917942265423f;
    float sstar = scalf[0];
    float w = 1.f - expf(sstar / Ds) / (expf(sd[0] / Ds) + expf(sd[1] / Ds));
    out[0] = w * sstar;
  }
}

extern "C" void kernel_launch(void* const* d_in, const int* in_sizes, int n_in,
                              void* d_out, int out_size, void* d_ws, size_t ws_size,
                              hipStream_t stream) {
  const float* patch = (const float*)d_in[0];
  const float* lib = (const float*)d_in[1];
  float* out = (float*)d_out;
  char* ws = (char*)d_ws;

  const size_t SZ_BPLANE = (size_t)NLPAD * DIM;              // 76,824,576 (int8)
  const size_t SZ_APLANE = (size_t)MPAD * DIM;               // 344,064 (int8)
  const size_t SZ_PART = (size_t)PCOLS * MPAD * 4;           // 11,203,584
  const size_t SZ_LIST = (size_t)NP * PCOLS * 4;             // 9,803,136
  const size_t SZ_WD2 = (size_t)NLPAD * 4;                   // 800,256
  const size_t NEED = SZ_BPLANE + SZ_APLANE + SZ_PART + SZ_LIST + SZ_WD2 + 4 * 1024 * 1024;

  if (ws_size >= NEED) {
    size_t off = 0;
    unsigned char* Bq = (unsigned char*)(ws + off); off += SZ_BPLANE;
    unsigned char* Aq = (unsigned char*)(ws + off); off += SZ_APLANE;
    float* partial = (float*)(ws + off); off += SZ_PART;
    unsigned int* list = (unsigned int*)(ws + off); off += SZ_LIST;
    float* wd2 = (float*)(ws + off); off += SZ_WD2;
    float* b2 = (float*)(ws + off); off += (size_t)NLPAD * 4;
    float* a2 = (float*)(ws + off); off += (size_t)MPAD * 4;
    unsigned long long* pmin = (unsigned long long*)(ws + off); off += NP * 8;
    unsigned long long* top3w = (unsigned long long*)(ws + off); off += WTOP_BLOCKS * 3 * 8;
    unsigned int* wlist = (unsigned int*)(ws + off); off += WCAP * 4;
    unsigned int* gmin = (unsigned int*)(ws + off); off += MPAD * 4;
    float* scalf = (float*)(ws + off); off += 16;
    int* scali = (int*)(ws + off); off += 16;
    unsigned int* cnt = (unsigned int*)(ws + off); off += 32;  // [0]=cnt [1]=wcnt

    k_prep<<<PREP_GRID, 256, 0, stream>>>(lib, patch, (unsigned*)Bq, (unsigned*)Aq,
                                          b2, a2, pmin, cnt, gmin);
    k_gemm<<<MTILES * NTILES, 256, 0, stream>>>(Aq, Bq, b2, partial);
    k_colmin<<<SCAN_BLOCKS, 256, 0, stream>>>(partial, gmin);
    k_select<<<SCAN_BLOCKS, 256, 0, stream>>>(partial, gmin, list, cnt);
    k_rescore<<<RESCORE_WAVES / 4, 256, 0, stream>>>(list, cnt, patch, lib, a2, b2, pmin);
    k_finres<<<RESIZE_BLOCKS + 1, 256, 0, stream>>>(pmin, scalf, scali, out);
    k_wdist<<<WTOP_BLOCKS, 256, 0, stream>>>((unsigned*)Bq, b2, scali, wd2, top3w);
    k_wsel1<<<1, 256, 0, stream>>>(top3w, scalf);
    k_wsel2<<<256, 256, 0, stream>>>(wd2, scalf, wlist, cnt + 1);
    k_finals2<<<1, 256, 0, stream>>>(patch, lib, b2, wlist, cnt + 1, scalf, scali, out);
  } else {
    // fallback: fp32 VALU path (verified R1)
    float* b2 = (float*)ws;
    float* a2 = (float*)(ws + 800000);
    unsigned long long* pmin = (unsigned long long*)(ws + 803200);
    unsigned long long* top3 = (unsigned long long*)(ws + 809472);
    float* scalf = (float*)(ws + 824896);
    int* scali = (int*)(ws + 824912);

    hipMemsetAsync(pmin, 0xFF, NP * sizeof(unsigned long long), stream);
    k_norms<<<(NL + NP + 3) / 4, 256, 0, stream>>>(patch, lib, a2, b2);
    dim3 grid(NL / 64, (NP + 63) / 64);
    k_distmin<<<grid, 256, 0, stream>>>(patch, lib, a2, b2, pmin);
    k_finres<<<RESIZE_BLOCKS + 1, 256, 0, stream>>>(pmin, scalf, scali, out);
    k_wtop<<<WTOP_BLOCKS, 256, 0, stream>>>(lib, scali, top3);
    k_finals<<<1, 256, 0, stream>>>(patch, lib, top3, scalf, scali, out);
  }
}

// Round 18
// 482.603 us; speedup vs baseline: 1.3394x; 1.0014x over previous
//
#include <hip/hip_runtime.h>

#define NP 784
#define DIM 384
#define NL 200000
#define WTOP_BLOCKS 512
#define WCAP 4096

#define BM 128
#define BN 128
#define BK 64
#define NSTEP 6
#define MTILES 7
#define NTILES 1563
#define MPAD (MTILES * BM)     // 896
#define NLPAD (NTILES * BN)    // 200064
#define PCOLS (NTILES * 2)     // 3126 granules of 64 j's per i
#define DELTA2 3.0f            // margin on approx val (i8 screen)
#define DELTAW 6.0f            // margin for w_dist top-3 selection
#define RESCORE_WAVES 2048

#define QS (6.5f / 127.0f)
#define QINV (127.0f / 6.5f)
#define NEG2S2 (-2.0f * QS * QS)
#define S2 (QS * QS)

#define PB_ROWS 96
#define PB_F4 (PB_ROWS * 96)       // 9216 float4 per block
#define PB_ITERS (PB_F4 / 256)     // 36
#define PB_GRID (NLPAD / PB_ROWS)  // 2084 (exact)
#define PREP_GRID (PB_GRID + MPAD / 4)  // 2308

#define SCAN_BLOCKS 96
#define GCHUNK ((PCOLS + SCAN_BLOCKS - 1) / SCAN_BLOCKS)  // 33

#define WD_WAVES (WTOP_BLOCKS * 4)                         // 2048
#define WD_CHUNK ((NL + WD_WAVES - 1) / WD_WAVES)          // 98

#define RESIZE_BLOCKS 196      // 196*256 = 50176 = 224*224

typedef __attribute__((ext_vector_type(4))) int int4v;

__device__ __forceinline__ unsigned long long packdj(float d2, int j) {
  return ((unsigned long long)__float_as_uint(d2) << 32) | (unsigned int)j;
}

__device__ __forceinline__ void ins3(unsigned long long &t0, unsigned long long &t1,
                                     unsigned long long &t2, unsigned long long p) {
  if (p < t0) { t2 = t1; t1 = t0; t0 = p; }
  else if (p < t1) { t2 = t1; t1 = p; }
  else if (p < t2) { t2 = p; }
}

// monotone f32 <-> u32 order-preserving encoding
__device__ __forceinline__ unsigned fenc(float x) {
  unsigned u = __float_as_uint(x);
  return (u & 0x80000000u) ? ~u : (u | 0x80000000u);
}
__device__ __forceinline__ float fdec(unsigned e) {
  unsigned u = (e & 0x80000000u) ? (e ^ 0x80000000u) : ~e;
  return __uint_as_float(u);
}

__device__ __forceinline__ int qclamp(float x) {
  int q = (int)rintf(x * QINV);
  return max(-127, min(127, q));
}
__device__ __forceinline__ unsigned qpack4(float4 v) {
  int q0 = qclamp(v.x), q1 = qclamp(v.y), q2 = qclamp(v.z), q3 = qclamp(v.w);
  return (unsigned)(q0 & 255) | ((unsigned)(q1 & 255) << 8) |
         ((unsigned)(q2 & 255) << 16) | ((unsigned)(q3 & 255) << 24);
}

#if __has_builtin(__builtin_amdgcn_sdot4)
__device__ __forceinline__ int dot4acc(unsigned a, unsigned b, int c) {
  return __builtin_amdgcn_sdot4((int)a, (int)b, c, false);
}
#else
__device__ __forceinline__ int dot4acc(unsigned a, unsigned b, int c) {
#pragma unroll
  for (int k = 0; k < 4; ++k)
    c += ((int)(signed char)((a >> (8 * k)) & 255)) *
         ((int)(signed char)((b >> (8 * k)) & 255));
  return c;
}
#endif
// R8-verified conflict-free swizzle for 64B rows / 4x16B chunks (0 conflicts measured).
// R12's (row^(row>>2))&3 gave 8.4M conflicts on the same pattern.
__device__ __forceinline__ int swz(int row) { return (row >> 1) & 3; }

// ========== merged prep: blocks [0,PB_GRID) quantize lib; rest quantize patch ==========
__global__ __launch_bounds__(256) void k_prep(const float* __restrict__ lib,
                                              const float* __restrict__ patch,
                                              unsigned* __restrict__ Bq4,
                                              unsigned* __restrict__ Aq4,
                                              float* __restrict__ b2,
                                              float* __restrict__ a2,
                                              unsigned long long* __restrict__ pmin,
                                              unsigned int* __restrict__ cnt,
                                              unsigned int* __restrict__ gmin) {
  const int t = threadIdx.x;
  if (blockIdx.x < PB_GRID) {
    __shared__ float rs[PB_ROWS][2];
    const int w = t >> 6, lane = t & 63;
    const size_t gbase = (size_t)blockIdx.x * PB_F4;
    const int rbase = blockIdx.x * PB_ROWS;
    const float4* lib4 = (const float4*)lib;
    const size_t NF4REAL = (size_t)NL * 96;

    for (int it = 0; it < PB_ITERS; ++it) {
      int fl = it * 256 + t;
      size_t f = gbase + fl;
      float4 v = make_float4(0.f, 0.f, 0.f, 0.f);
      if (f < NF4REAL) v = lib4[f];
      float sum = fmaf(v.x, v.x, fmaf(v.y, v.y, fmaf(v.z, v.z, v.w * v.w)));
      Bq4[f] = qpack4(v);

      int wstart = it * 256 + (w << 6);
      int r0 = wstart / 96;
      int s = (r0 + 1) * 96 - wstart;          // in {32, 64, 96}
      float lo = (lane < s) ? sum : 0.f;
#pragma unroll
      for (int m = 1; m < 64; m <<= 1) lo += __shfl_xor(lo, m);
      if (lane == 0) rs[r0][(s == 96) ? 0 : 1] = lo;
      if (s == 32) {
        float hi = (lane >= 32) ? sum : 0.f;
#pragma unroll
        for (int m = 1; m < 64; m <<= 1) hi += __shfl_xor(hi, m);
        if (lane == 0) rs[r0 + 1][0] = hi;
      }
    }
    __syncthreads();
    if (t < PB_ROWS) {
      int r = rbase + t;
      b2[r] = (r < NL) ? (rs[t][0] + rs[t][1]) : INFINITY;
    }
  } else {
    int ab = blockIdx.x - PB_GRID;
    if (ab == 0) {
      for (int q = t; q < NP; q += 256) pmin[q] = ~0ull;
      for (int q = t; q < MPAD; q += 256) gmin[q] = 0xFFFFFFFFu;
      if (t < 8) cnt[t] = 0;
    }
    int i = (ab << 2) | (t >> 6);
    int lane = t & 63;
    if (i >= MPAD) return;
    unsigned* orow = Aq4 + (size_t)i * 96;
    if (i < NP) {
      const float4* r4 = (const float4*)(patch + (size_t)i * DIM);
      float s = 0.f;
      float4 v = r4[lane];
      s = fmaf(v.x, v.x, fmaf(v.y, v.y, fmaf(v.z, v.z, fmaf(v.w, v.w, s))));
      orow[lane] = qpack4(v);
      if (lane < 32) {
        float4 v1 = r4[64 + lane];
        s = fmaf(v1.x, v1.x, fmaf(v1.y, v1.y, fmaf(v1.z, v1.z, fmaf(v1.w, v1.w, s))));
        orow[64 + lane] = qpack4(v1);
      }
#pragma unroll
      for (int m = 1; m < 64; m <<= 1) s += __shfl_xor(s, m);
      if (lane == 0) a2[i] = s;
    } else {
      orow[lane] = 0u;
      if (lane < 32) orow[64 + lane] = 0u;
    }
  }
}

// ====== main: 128x128 i8 MFMA GEMM, BK=64, dbuf 2-phase prefetch [R12/R14/R17-verified] ======
__global__ __launch_bounds__(256, 4) void k_gemm(const unsigned char* __restrict__ Aq,
                                                 const unsigned char* __restrict__ Bq,
                                                 const float* __restrict__ b2,
                                                 float* __restrict__ partial) {
  __shared__ char sA[16384], sB[16384];   // 2 x 8KB each, 32KB total

  const int TOT = MTILES * NTILES;        // 10941
  const int q8 = TOT >> 3, r8 = TOT & 7;  // 1367, 5
  int xcd = blockIdx.x & 7, seq = blockIdx.x >> 3;
  int wg = (xcd < r8 ? xcd * (q8 + 1) : r8 * (q8 + 1) + (xcd - r8) * q8) + seq;
  int ntile = wg / MTILES;
  int mtile = wg - ntile * MTILES;
  const int i0 = mtile * BM;
  const int j0 = ntile * BN;

  const int t = threadIdx.x;
  const int w = t >> 6, lane = t & 63;
  const int wr = w >> 1, wc = w & 1;        // wave -> 64x64 sub-tile
  const int lrow = lane & 15, lk = lane >> 4;

  const char* srcs[4];
  int dslot[4];
  {
    int s0 = t, s1 = 256 + t;
    int r0 = s0 >> 2, c0 = (s0 & 3) ^ swz(r0);
    int r1 = s1 >> 2, c1 = (s1 & 3) ^ swz(r1);
    srcs[0] = (const char*)Aq + (size_t)(i0 + r0) * DIM + (c0 << 4);
    srcs[1] = (const char*)Aq + (size_t)(i0 + r1) * DIM + (c1 << 4);
    srcs[2] = (const char*)Bq + (size_t)(j0 + r0) * DIM + (c0 << 4);
    srcs[3] = (const char*)Bq + (size_t)(j0 + r1) * DIM + (c1 << 4);
    dslot[0] = s0 << 4; dslot[1] = s1 << 4;
    dslot[2] = s0 << 4; dslot[3] = s1 << 4;
  }

  int aoffs[4], boffs[4];
#pragma unroll
  for (int m = 0; m < 4; ++m) {
    int Ra = (wr << 6) + (m << 4) + lrow;
    aoffs[m] = (Ra << 6) + ((lk ^ swz(Ra)) << 4);
    int Rb = (wc << 6) + (m << 4) + lrow;
    boffs[m] = (Rb << 6) + ((lk ^ swz(Rb)) << 4);
  }

  int4v acc[4][4];
#pragma unroll
  for (int m = 0; m < 4; ++m)
#pragma unroll
    for (int n = 0; n < 4; ++n) acc[m][n] = (int4v){0, 0, 0, 0};

  __builtin_amdgcn_global_load_lds((const __attribute__((address_space(1))) void*)srcs[0],
                                   (__attribute__((address_space(3))) void*)(sA + dslot[0]), 16, 0, 0);
  __builtin_amdgcn_global_load_lds((const __attribute__((address_space(1))) void*)srcs[1],
                                   (__attribute__((address_space(3))) void*)(sA + dslot[1]), 16, 0, 0);
  __builtin_amdgcn_global_load_lds((const __attribute__((address_space(1))) void*)srcs[2],
                                   (__attribute__((address_space(3))) void*)(sB + dslot[2]), 16, 0, 0);
  __builtin_amdgcn_global_load_lds((const __attribute__((address_space(1))) void*)srcs[3],
                                   (__attribute__((address_space(3))) void*)(sB + dslot[3]), 16, 0, 0);
  __syncthreads();

#pragma unroll
  for (int step = 0; step < NSTEP; ++step) {
    const int cur = step & 1;
    const int curoff = cur << 13;
    if (step < NSTEP - 1) {
      const int nxtoff = (cur ^ 1) << 13;
      const int kb = (step + 1) << 6;
      __builtin_amdgcn_global_load_lds((const __attribute__((address_space(1))) void*)(srcs[0] + kb),
                                       (__attribute__((address_space(3))) void*)(sA + nxtoff + dslot[0]), 16, 0, 0);
      __builtin_amdgcn_global_load_lds((const __attribute__((address_space(1))) void*)(srcs[1] + kb),
                                       (__attribute__((address_space(3))) void*)(sA + nxtoff + dslot[1]), 16, 0, 0);
      __builtin_amdgcn_global_load_lds((const __attribute__((address_space(1))) void*)(srcs[2] + kb),
                                       (__attribute__((address_space(3))) void*)(sB + nxtoff + dslot[2]), 16, 0, 0);
      __builtin_amdgcn_global_load_lds((const __attribute__((address_space(1))) void*)(srcs[3] + kb),
                                       (__attribute__((address_space(3))) void*)(sB + nxtoff + dslot[3]), 16, 0, 0);
    }
    int4v fa[4], fb[4];
#pragma unroll
    for (int m = 0; m < 4; ++m) fa[m] = *(const int4v*)(sA + curoff + aoffs[m]);
#pragma unroll
    for (int n = 0; n < 4; ++n) fb[n] = *(const int4v*)(sB + curoff + boffs[n]);
#pragma unroll
    for (int m = 0; m < 4; ++m)
#pragma unroll
      for (int n = 0; n < 4; ++n)
        acc[m][n] = __builtin_amdgcn_mfma_i32_16x16x64_i8(fa[m], fb[n], acc[m][n], 0, 0, 0);
    if (step < NSTEP - 1) __syncthreads();
  }

  float b2v[4];
#pragma unroll
  for (int n = 0; n < 4; ++n) b2v[n] = b2[j0 + (wc << 6) + (n << 4) + lrow];
  const int gcol = (ntile << 1) + wc;
  float* pcol = partial + (size_t)gcol * MPAD;
#pragma unroll
  for (int m = 0; m < 4; ++m) {
    float4 v;
#pragma unroll
    for (int r = 0; r < 4; ++r) {
      float dm = INFINITY;
#pragma unroll
      for (int n = 0; n < 4; ++n)
        dm = fminf(dm, fmaf(NEG2S2, (float)acc[m][n][r], b2v[n]));
#pragma unroll
      for (int mm = 1; mm < 16; mm <<= 1)
        dm = fminf(dm, __shfl_xor(dm, mm));
      ((float*)&v)[r] = dm;
    }
    if (lrow == 0)
      *(float4*)(pcol + i0 + (wr << 6) + (m << 4) + (lk << 2)) = v;
  }
}

// ===== column min over gcols (coalesced): per-i global min via encoded atomicMin =====
__global__ __launch_bounds__(256) void k_colmin(const float* __restrict__ partial,
                                                unsigned int* __restrict__ gmin) {
  int t = threadIdx.x;
  int g0 = blockIdx.x * GCHUNK;
  int g1 = min(g0 + GCHUNK, PCOLS);
  float mv0 = INFINITY, mv1 = INFINITY, mv2 = INFINITY, mv3 = INFINITY;
  for (int g = g0; g < g1; ++g) {
    const float* col = partial + (size_t)g * MPAD;
    mv0 = fminf(mv0, col[t]);
    mv1 = fminf(mv1, col[t + 256]);
    mv2 = fminf(mv2, col[t + 512]);
    if (t < 128) mv3 = fminf(mv3, col[t + 768]);
  }
  atomicMin(&gmin[t], fenc(mv0));
  atomicMin(&gmin[t + 256], fenc(mv1));
  atomicMin(&gmin[t + 512], fenc(mv2));
  if (t < 128) atomicMin(&gmin[t + 768], fenc(mv3));
}

// ===== select candidates within margin (coalesced read) -> compacted list =====
__global__ __launch_bounds__(256) void k_select(const float* __restrict__ partial,
                                                const unsigned int* __restrict__ gmin,
                                                unsigned int* __restrict__ list,
                                                unsigned int* __restrict__ cnt) {
  int t = threadIdx.x;
  int g0 = blockIdx.x * GCHUNK;
  int g1 = min(g0 + GCHUNK, PCOLS);
  float th0 = fdec(gmin[t]) + DELTA2;
  float th1 = fdec(gmin[t + 256]) + DELTA2;
  float th2 = fdec(gmin[t + 512]) + DELTA2;
  float th3 = (t < 16) ? (fdec(gmin[t + 768]) + DELTA2) : -INFINITY;
  for (int g = g0; g < g1; ++g) {
    const float* col = partial + (size_t)g * MPAD;
    float v0 = col[t], v1 = col[t + 256], v2 = col[t + 512];
    float v3 = (t < 128) ? col[t + 768] : INFINITY;
    if (v0 <= th0) { unsigned p = atomicAdd(cnt, 1u); list[p] = ((unsigned)t << 12) | (unsigned)g; }
    if (v1 <= th1) { unsigned p = atomicAdd(cnt, 1u); list[p] = ((unsigned)(t + 256) << 12) | (unsigned)g; }
    if (v2 <= th2) { unsigned p = atomicAdd(cnt, 1u); list[p] = ((unsigned)(t + 512) << 12) | (unsigned)g; }
    if (t < 16 && v3 <= th3) { unsigned p = atomicAdd(cnt, 1u); list[p] = ((unsigned)(t + 768) << 12) | (unsigned)g; }
  }
}

// ===== exact fp32 rescore of candidate granules -> pmin (packed atomicMin) =====
__global__ __launch_bounds__(256) void k_rescore(const unsigned int* __restrict__ list,
                                                 const unsigned int* __restrict__ cnt,
                                                 const float* __restrict__ patch,
                                                 const float* __restrict__ lib,
                                                 const float* __restrict__ a2,
                                                 const float* __restrict__ b2,
                                                 unsigned long long* __restrict__ pmin) {
  int wid = (blockIdx.x << 2) | (threadIdx.x >> 6);
  int lane = threadIdx.x & 63;
  int n = (int)*cnt;
  for (int c = wid; c < n; c += RESCORE_WAVES) {
    unsigned int e = list[c];
    int i = (int)(e >> 12);
    int g = (int)(e & 4095u);
    int j = (g << 6) + lane;
    unsigned long long best = ~0ull;
    if (j < NL) {
      const float* pr = patch + (size_t)i * DIM;
      const float* lr = lib + (size_t)j * DIM;
      float d0 = 0.f, d1 = 0.f, d2s = 0.f, d3 = 0.f;
#pragma unroll 8
      for (int k = 0; k < DIM; k += 4) {
        float4 lv = *(const float4*)(lr + k);
        float4 pv = *(const float4*)(pr + k);
        d0 = fmaf(lv.x, pv.x, d0);
        d1 = fmaf(lv.y, pv.y, d1);
        d2s = fmaf(lv.z, pv.z, d2s);
        d3 = fmaf(lv.w, pv.w, d3);
      }
      float dot = (d0 + d1) + (d2s + d3);
      float d2 = fmaxf(a2[i] + b2[j] - 2.f * dot, 0.f);
      best = packdj(d2, j);
    }
#pragma unroll
    for (int mm = 1; mm < 64; mm <<= 1) {
      unsigned long long o = __shfl_xor(best, mm);
      best = (o < best) ? o : best;
    }
    if (lane == 0) atomicMin(pmin + i, best);
  }
}

// ===== fused finalize + resize: blocks 0..195 resize; block 196 computes s_star/s_idx =====
__global__ __launch_bounds__(256) void k_finres(const unsigned long long* __restrict__ pmin,
                                                float* __restrict__ scalf,
                                                int* __restrict__ scali,
                                                float* __restrict__ out) {
  int t = threadIdx.x;
  if (blockIdx.x < RESIZE_BLOCKS) {
    int o = blockIdx.x * 256 + t;
    int y = o / 224, x = o - y * 224;
    float sy = (y + 0.5f) * 0.125f - 0.5f;
    float sx = (x + 0.5f) * 0.125f - 0.5f;
    int y0 = (int)floorf(sy); float fy = sy - (float)y0;
    int x0 = (int)floorf(sx); float fx = sx - (float)x0;
    int y0c = max(y0, 0), y1c = min(y0 + 1, 27);
    int x0c = max(x0, 0), x1c = min(x0 + 1, 27);
#define MV(idx) sqrtf(__uint_as_float((unsigned int)(pmin[idx] >> 32)))
    float v00 = MV(y0c * 28 + x0c), v01 = MV(y0c * 28 + x1c);
    float v10 = MV(y1c * 28 + x0c), v11 = MV(y1c * 28 + x1c);
#undef MV
    float v0 = v00 + fx * (v01 - v00);
    float v1 = v10 + fx * (v11 - v10);
    out[1 + o] = v0 + fy * (v1 - v0);
  } else {
    __shared__ float sv[256];
    __shared__ int si[256];
    float bv = -1.f; int bi = 1 << 30;
    for (int i = t; i < NP; i += 256) {
      float v = sqrtf(__uint_as_float((unsigned int)(pmin[i] >> 32)));
      if (v > bv) { bv = v; bi = i; }
    }
    sv[t] = bv; si[t] = bi;
    __syncthreads();
    for (int s = 128; s > 0; s >>= 1) {
      if (t < s) {
        if (sv[t + s] > sv[t] || (sv[t + s] == sv[t] && si[t + s] < si[t])) {
          sv[t] = sv[t + s]; si[t] = si[t + s];
        }
      }
      __syncthreads();
    }
    if (t == 0) {
      scalf[0] = sv[0];
      scali[0] = si[0];
      scali[1] = (int)(unsigned int)(pmin[si[0]] & 0xFFFFFFFFull);
    }
  }
}

// ===== approx w_dist^2: contiguous per-wave chunks, 2-row unrolled [R14-verified] =====
__global__ __launch_bounds__(256) void k_wdist(const unsigned* __restrict__ Bq4,
                                               const float* __restrict__ b2,
                                               const int* __restrict__ scali,
                                               float* __restrict__ wd2,
                                               unsigned long long* __restrict__ top3w) {
  __shared__ unsigned long long sm[12];
  int wave = threadIdx.x >> 6, lane = threadIdx.x & 63;
  int jstar = scali[1];
  const unsigned* msrow = Bq4 + (size_t)jstar * 96;
  unsigned m0 = msrow[lane];
  unsigned m1 = (lane < 32) ? msrow[64 + lane] : 0u;
  float bstar = b2[jstar];
  unsigned long long t0 = ~0ull, t1 = ~0ull, t2 = ~0ull;
  int wid = (blockIdx.x << 2) | wave;
  int r0 = wid * WD_CHUNK;
  int rend = min(r0 + WD_CHUNK, NL);
  for (int j = r0; j + 1 < rend; j += 2) {
    const unsigned* rowa = Bq4 + (size_t)j * 96;
    const unsigned* rowb = rowa + 96;
    unsigned a0 = rowa[lane], b0 = rowb[lane];
    unsigned a1 = 0u, b1 = 0u;
    if (lane < 32) { a1 = rowa[64 + lane]; b1 = rowb[64 + lane]; }
    int ia = dot4acc(m0, a0, 0);
    int ib = dot4acc(m0, b0, 0);
    if (lane < 32) { ia = dot4acc(m1, a1, ia); ib = dot4acc(m1, b1, ib); }
#pragma unroll
    for (int mm = 1; mm < 64; mm <<= 1) {
      ia += __shfl_xor(ia, mm);
      ib += __shfl_xor(ib, mm);
    }
    float d2a = fmaxf(bstar + b2[j] - 2.f * S2 * (float)ia, 0.f);
    float d2b = fmaxf(bstar + b2[j + 1] - 2.f * S2 * (float)ib, 0.f);
    if (lane == 0) { wd2[j] = d2a; wd2[j + 1] = d2b; }
    ins3(t0, t1, t2, packdj(d2a, j));
    ins3(t0, t1, t2, packdj(d2b, j + 1));
  }
  if ((rend - r0) & 1) {
    int j = rend - 1;
    const unsigned* row = Bq4 + (size_t)j * 96;
    int id = dot4acc(m0, row[lane], 0);
    if (lane < 32) id = dot4acc(m1, row[64 + lane], id);
#pragma unroll
    for (int mm = 1; mm < 64; mm <<= 1) id += __shfl_xor(id, mm);
    float d2 = fmaxf(bstar + b2[j] - 2.f * S2 * (float)id, 0.f);
    if (lane == 0) wd2[j] = d2;
    ins3(t0, t1, t2, packdj(d2, j));
  }
  if (lane == 0) { sm[wave * 3] = t0; sm[wave * 3 + 1] = t1; sm[wave * 3 + 2] = t2; }
  __syncthreads();
  if (threadIdx.x == 0) {
    unsigned long long a0 = ~0ull, a1 = ~0ull, a2v = ~0ull;
    for (int e = 0; e < 12; ++e) ins3(a0, a1, a2v, sm[e]);
    top3w[blockIdx.x * 3 + 0] = a0;
    top3w[blockIdx.x * 3 + 1] = a1;
    top3w[blockIdx.x * 3 + 2] = a2v;
  }
}

// ===== merge approx top-3 -> threshold [verified R5/R12] =====
__global__ __launch_bounds__(256) void k_wsel1(const unsigned long long* __restrict__ top3w,
                                               float* __restrict__ scalf) {
  __shared__ unsigned long long sm[768];
  int t = threadIdx.x;
  unsigned long long t0 = ~0ull, t1 = ~0ull, t2 = ~0ull;
  for (int e = t; e < WTOP_BLOCKS * 3; e += 256) ins3(t0, t1, t2, top3w[e]);
  sm[t] = t0; sm[256 + t] = t1; sm[512 + t] = t2;
  __syncthreads();
  if (t == 0) {
    unsigned long long a0 = ~0ull, a1 = ~0ull, a2v = ~0ull;
    for (int e = 0; e < 768; ++e) ins3(a0, a1, a2v, sm[e]);
    scalf[1] = __uint_as_float((unsigned int)(a2v >> 32)) + DELTAW;
  }
}

// ===== collect all j with wd2 <= thr [verified R5] =====
__global__ __launch_bounds__(256) void k_wsel2(const float* __restrict__ wd2,
                                               const float* __restrict__ scalf,
                                               unsigned int* __restrict__ wlist,
                                               unsigned int* __restrict__ wcnt) {
  float thr = scalf[1];
  for (int j = blockIdx.x * 256 + threadIdx.x; j < NL; j += 256 * 256) {
    if (wd2[j] <= thr) {
      unsigned int pos = atomicAdd(wcnt, 1u);
      if (pos < WCAP) wlist[pos] = (unsigned int)j;
    }
  }
}

// ===== exact rescore of w candidates -> top-3 -> final s [verified R5] =====
__global__ __launch_bounds__(256) void k_finals2(const float* __restrict__ patch,
                                                 const float* __restrict__ lib,
                                                 const float* __restrict__ b2,
                                                 const unsigned int* __restrict__ wlist,
                                                 const unsigned int* __restrict__ wcnt,
                                                 const float* __restrict__ scalf,
                                                 const int* __restrict__ scali,
                                                 float* __restrict__ out) {
  __shared__ unsigned long long pk[WCAP];
  __shared__ int snn[2];
  __shared__ float sd[2];
  int t = threadIdx.x, wv = t >> 6, lane = t & 63;
  int n = min((int)*wcnt, WCAP);
  int jstar = scali[1];
  const float* mstar = lib + (size_t)jstar * DIM;
  float bstar = b2[jstar];
  for (int c = wv; c < n; c += 4) {
    int j = (int)wlist[c];
    const float* lr = lib + (size_t)j * DIM;
    float s = 0.f;
#pragma unroll
    for (int q = 0; q < 6; ++q)
      s = fmaf(mstar[lane + (q << 6)], lr[lane + (q << 6)], s);
#pragma unroll
    for (int mm = 1; mm < 64; mm <<= 1) s += __shfl_xor(s, mm);
    if (lane == 0) pk[c] = packdj(fmaxf(bstar + b2[j] - 2.f * s, 0.f), j);
  }
  __syncthreads();
  if (t == 0) {
    unsigned long long a0 = ~0ull, a1 = ~0ull, a2v = ~0ull;
    for (int e = 0; e < n; ++e) ins3(a0, a1, a2v, pk[e]);
    snn[0] = (int)(unsigned int)(a1 & 0xFFFFFFFFull);
    snn[1] = (int)(unsigned int)(a2v & 0xFFFFFFFFull);
  }
  __syncthreads();
  if (t < 128) {
    const float* mt = patch + (size_t)scali[0] * DIM;
    const float* bp = lib + (size_t)snn[wv] * DIM;
    float s = 0.f;
#pragma unroll
    for (int q = 0; q < 6; ++q) {
      float d = mt[lane + (q << 6)] - bp[lane + (q << 6)];
      s = fmaf(d, d, s);
    }
#pragma unroll
    for (int mm = 1; mm < 64; mm <<= 1) s += __shfl_xor(s, mm);
    if (lane == 0) sd[wv] = sqrtf(fmaxf(s, 0.f));
  }
  __syncthreads();
  if (t == 0) {
    const float Ds = 19.595917942265423f;  // sqrt(384)
    float sstar = scalf[0];
    float w = 1.f - expf(sstar / Ds) / (expf(sd[0] / Ds) + expf(sd[1] / Ds));
    out[0] = w * sstar;
  }
}

// ======= fallback fp32 path kernels (used only if ws_size is too small) =======
__global__ __launch_bounds__(256) void k_norms(const float* __restrict__ patch,
                                               const float* __restrict__ lib,
                                               float* __restrict__ a2,
                                               float* __restrict__ b2) {
  int wave = (blockIdx.x << 2) | (threadIdx.x >> 6);
  int lane = threadIdx.x & 63;
  const int NR = NL + NP;
  if (wave >= NR) return;
  const float* src = (wave < NL) ? (lib + (size_t)wave * DIM)
                                 : (patch + (size_t)(wave - NL) * DIM);
  float s = 0.f;
#pragma unroll
  for (int m = 0; m < 6; ++m) { float v = src[lane + (m << 6)]; s += v * v; }
#pragma unroll
  for (int m = 1; m < 64; m <<= 1) s += __shfl_xor(s, m);
  if (lane == 0) { if (wave < NL) b2[wave] = s; else a2[wave - NL] = s; }
}

__global__ __launch_bounds__(256) void k_distmin(const float* __restrict__ patch,
                                                 const float* __restrict__ lib,
                                                 const float* __restrict__ a2,
                                                 const float* __restrict__ b2,
                                                 unsigned long long* __restrict__ pmin) {
  __shared__ float As[16][68];
  __shared__ float Bs[16][68];
  const int t = threadIdx.x;
  const int lr = t >> 2;
  const int lc = (t & 3) << 2;
  const int ti = t >> 4;
  const int tj = t & 15;
  const int i0 = blockIdx.y << 6;
  const int j0 = blockIdx.x << 6;
  const bool a_ok = (i0 + lr) < NP;
  const float* ap = patch + (size_t)(i0 + lr) * DIM + lc;
  const float* bp = lib + (size_t)(j0 + lr) * DIM + lc;

  float acc[4][4] = {};
  for (int k0 = 0; k0 < DIM; k0 += 16) {
    float4 avv = make_float4(0.f, 0.f, 0.f, 0.f);
    if (a_ok) avv = *(const float4*)(ap + k0);
    float4 bvv = *(const float4*)(bp + k0);
    __syncthreads();
    As[lc + 0][lr] = avv.x; As[lc + 1][lr] = avv.y;
    As[lc + 2][lr] = avv.z; As[lc + 3][lr] = avv.w;
    Bs[lc + 0][lr] = bvv.x; Bs[lc + 1][lr] = bvv.y;
    Bs[lc + 2][lr] = bvv.z; Bs[lc + 3][lr] = bvv.w;
    __syncthreads();
#pragma unroll
    for (int kk = 0; kk < 16; ++kk) {
      float4 a = *(const float4*)&As[kk][ti << 2];
      float4 b = *(const float4*)&Bs[kk][tj << 2];
      acc[0][0] += a.x * b.x; acc[0][1] += a.x * b.y; acc[0][2] += a.x * b.z; acc[0][3] += a.x * b.w;
      acc[1][0] += a.y * b.x; acc[1][1] += a.y * b.y; acc[1][2] += a.y * b.z; acc[1][3] += a.y * b.w;
      acc[2][0] += a.z * b.x; acc[2][1] += a.z * b.y; acc[2][2] += a.z * b.z; acc[2][3] += a.z * b.w;
      acc[3][0] += a.w * b.x; acc[3][1] += a.w * b.y; acc[3][2] += a.w * b.z; acc[3][3] += a.w * b.w;
    }
  }
#pragma unroll
  for (int r = 0; r < 4; ++r) {
    int i = i0 + (ti << 2) + r;
    unsigned long long best = ~0ull;
    if (i < NP) {
      float ai = a2[i];
#pragma unroll
      for (int c = 0; c < 4; ++c) {
        int j = j0 + (tj << 2) + c;
        float d2 = fmaxf(ai + b2[j] - 2.f * acc[r][c], 0.f);
        unsigned long long p = packdj(d2, j);
        best = (p < best) ? p : best;
      }
    }
#pragma unroll
    for (int m = 1; m < 16; m <<= 1) {
      unsigned long long o = __shfl_xor(best, m);
      best = (o < best) ? o : best;
    }
    if (tj == 0 && i < NP) atomicMin(pmin + i, best);
  }
}

__global__ __launch_bounds__(256) void k_wtop(const float* __restrict__ lib,
                                              const int* __restrict__ scali,
                                              unsigned long long* __restrict__ top3) {
  __shared__ unsigned long long sm[12];
  int wave = threadIdx.x >> 6, lane = threadIdx.x & 63;
  int jstar = scali[1];
  const float* ms = lib + (size_t)jstar * DIM;
  float m[6];
#pragma unroll
  for (int q = 0; q < 6; ++q) m[q] = ms[lane + (q << 6)];
  unsigned long long t0 = ~0ull, t1 = ~0ull, t2 = ~0ull;
  int gw = (blockIdx.x << 2) | wave;
  for (int j = gw; j < NL; j += WTOP_BLOCKS * 4) {
    const float* bp = lib + (size_t)j * DIM;
    float s = 0.f;
#pragma unroll
    for (int q = 0; q < 6; ++q) { float d = bp[lane + (q << 6)] - m[q]; s += d * d; }
#pragma unroll
    for (int mm = 1; mm < 64; mm <<= 1) s += __shfl_xor(s, mm);
    ins3(t0, t1, t2, packdj(fmaxf(s, 0.f), j));
  }
  if (lane == 0) { sm[wave * 3] = t0; sm[wave * 3 + 1] = t1; sm[wave * 3 + 2] = t2; }
  __syncthreads();
  if (threadIdx.x == 0) {
    unsigned long long a0 = ~0ull, a1 = ~0ull, a2v = ~0ull;
    for (int e = 0; e < 12; ++e) ins3(a0, a1, a2v, sm[e]);
    top3[blockIdx.x * 3 + 0] = a0;
    top3[blockIdx.x * 3 + 1] = a1;
    top3[blockIdx.x * 3 + 2] = a2v;
  }
}

__global__ __launch_bounds__(256) void k_finals(const float* __restrict__ patch,
                                                const float* __restrict__ lib,
                                                const unsigned long long* __restrict__ top3,
                                                const float* __restrict__ scalf,
                                                const int* __restrict__ scali,
                                                float* __restrict__ out) {
  __shared__ unsigned long long sm[768];
  __shared__ int snn[2];
  __shared__ float sd[2];
  int t = threadIdx.x;
  unsigned long long t0 = ~0ull, t1 = ~0ull, t2 = ~0ull;
  for (int e = t; e < WTOP_BLOCKS * 3; e += 256) ins3(t0, t1, t2, top3[e]);
  sm[t] = t0; sm[256 + t] = t1; sm[512 + t] = t2;
  __syncthreads();
  if (t == 0) {
    unsigned long long a0 = ~0ull, a1 = ~0ull, a2v = ~0ull;
    for (int e = 0; e < 768; ++e) ins3(a0, a1, a2v, sm[e]);
    snn[0] = (int)(unsigned int)(a1 & 0xFFFFFFFFull);
    snn[1] = (int)(unsigned int)(a2v & 0xFFFFFFFFull);
  }
  __syncthreads();
  if (t < 128) {
    int wv = t >> 6, lane = t & 63;
    const float* mt = patch + (size_t)scali[0] * DIM;
    const float* bp = lib + (size_t)snn[wv] * DIM;
    float s = 0.f;
#pragma unroll
    for (int q = 0; q < 6; ++q) {
      float d = mt[lane + (q << 6)] - bp[lane + (q << 6)];
      s += d * d;
    }
#pragma unroll
    for (int mm = 1; mm < 64; mm <<= 1) s += __shfl_xor(s, mm);
    if (lane == 0) sd[wv] = sqrtf(fmaxf(s, 0.f));
  }
  __syncthreads();
  if (t == 0) {
    const float Ds = 19.595917942265423f;
    float sstar = scalf[0];
    float w = 1.f - expf(sstar / Ds) / (expf(sd[0] / Ds) + expf(sd[1] / Ds));
    out[0] = w * sstar;
  }
}

extern "C" void kernel_launch(void* const* d_in, const int* in_sizes, int n_in,
                              void* d_out, int out_size, void* d_ws, size_t ws_size,
                              hipStream_t stream) {
  const float* patch = (const float*)d_in[0];
  const float* lib = (const float*)d_in[1];
  float* out = (float*)d_out;
  char* ws = (char*)d_ws;

  const size_t SZ_BPLANE = (size_t)NLPAD * DIM;              // 76,824,576 (int8)
  const size_t SZ_APLANE = (size_t)MPAD * DIM;               // 344,064 (int8)
  const size_t SZ_PART = (size_t)PCOLS * MPAD * 4;           // 11,203,584
  const size_t SZ_LIST = (size_t)NP * PCOLS * 4;             // 9,803,136
  const size_t SZ_WD2 = (size_t)NLPAD * 4;                   // 800,256
  const size_t NEED = SZ_BPLANE + SZ_APLANE + SZ_PART + SZ_LIST + SZ_WD2 + 4 * 1024 * 1024;

  if (ws_size >= NEED) {
    size_t off = 0;
    unsigned char* Bq = (unsigned char*)(ws + off); off += SZ_BPLANE;
    unsigned char* Aq = (unsigned char*)(ws + off); off += SZ_APLANE;
    float* partial = (float*)(ws + off); off += SZ_PART;
    unsigned int* list = (unsigned int*)(ws + off); off += SZ_LIST;
    float* wd2 = (float*)(ws + off); off += SZ_WD2;
    float* b2 = (float*)(ws + off); off += (size_t)NLPAD * 4;
    float* a2 = (float*)(ws + off); off += (size_t)MPAD * 4;
    unsigned long long* pmin = (unsigned long long*)(ws + off); off += NP * 8;
    unsigned long long* top3w = (unsigned long long*)(ws + off); off += WTOP_BLOCKS * 3 * 8;
    unsigned int* wlist = (unsigned int*)(ws + off); off += WCAP * 4;
    unsigned int* gmin = (unsigned int*)(ws + off); off += MPAD * 4;
    float* scalf = (float*)(ws + off); off += 16;
    int* scali = (int*)(ws + off); off += 16;
    unsigned int* cnt = (unsigned int*)(ws + off); off += 32;  // [0]=cnt [1]=wcnt

    k_prep<<<PREP_GRID, 256, 0, stream>>>(lib, patch, (unsigned*)Bq, (unsigned*)Aq,
                                          b2, a2, pmin, cnt, gmin);
    k_gemm<<<MTILES * NTILES, 256, 0, stream>>>(Aq, Bq, b2, partial);
    k_colmin<<<SCAN_BLOCKS, 256, 0, stream>>>(partial, gmin);
    k_select<<<SCAN_BLOCKS, 256, 0, stream>>>(partial, gmin, list, cnt);
    k_rescore<<<RESCORE_WAVES / 4, 256, 0, stream>>>(list, cnt, patch, lib, a2, b2, pmin);
    k_finres<<<RESIZE_BLOCKS + 1, 256, 0, stream>>>(pmin, scalf, scali, out);
    k_wdist<<<WTOP_BLOCKS, 256, 0, stream>>>((unsigned*)Bq, b2, scali, wd2, top3w);
    k_wsel1<<<1, 256, 0, stream>>>(top3w, scalf);
    k_wsel2<<<256, 256, 0, stream>>>(wd2, scalf, wlist, cnt + 1);
    k_finals2<<<1, 256, 0, stream>>>(patch, lib, b2, wlist, cnt + 1, scalf, scali, out);
  } else {
    // fallback: fp32 VALU path (verified R1)
    float* b2 = (float*)ws;
    float* a2 = (float*)(ws + 800000);
    unsigned long long* pmin = (unsigned long long*)(ws + 803200);
    unsigned long long* top3 = (unsigned long long*)(ws + 809472);
    float* scalf = (float*)(ws + 824896);
    int* scali = (int*)(ws + 824912);

    hipMemsetAsync(pmin, 0xFF, NP * sizeof(unsigned long long), stream);
    k_norms<<<(NL + NP + 3) / 4, 256, 0, stream>>>(patch, lib, a2, b2);
    dim3 grid(NL / 64, (NP + 63) / 64);
    k_distmin<<<grid, 256, 0, stream>>>(patch, lib, a2, b2, pmin);
    k_finres<<<RESIZE_BLOCKS + 1, 256, 0, stream>>>(pmin, scalf, scali, out);
    k_wtop<<<WTOP_BLOCKS, 256, 0, stream>>>(lib, scali, top3);
    k_finals<<<1, 256, 0, stream>>>(patch, lib, top3, scalf, scali, out);
  }
}